// Round 16
// baseline (596.268 us; speedup 1.0000x reference)
//
#include <hip/hip_runtime.h>

#define NTOK   25088          // B*P = 128*196
#define HIDD   768
#define NHEAD  12
#define HDIM   64
#define FFD    3072
#define NPAT   196
#define QKVS   2304           // interleaved qkv row stride

typedef __attribute__((ext_vector_type(8))) short short8;
typedef __attribute__((ext_vector_type(8))) __bf16 bf16x8;
typedef __attribute__((ext_vector_type(4))) float f32x4;
typedef __attribute__((ext_vector_type(4))) float fl4;
typedef __attribute__((ext_vector_type(4))) unsigned short us4;
typedef __attribute__((ext_vector_type(8))) unsigned short us8;

#define AS1 __attribute__((address_space(1)))
#define AS3 __attribute__((address_space(3)))

__device__ __forceinline__ unsigned short f2bf(float f) {
  unsigned int u = __builtin_bit_cast(unsigned int, f);
  u += 0x7FFFu + ((u >> 16) & 1u);
  return (unsigned short)(u >> 16);
}
__device__ __forceinline__ float bf2f(unsigned short h) {
  unsigned int u = ((unsigned int)h) << 16;
  return __builtin_bit_cast(float, u);
}

// ---- MFMA wrapper: SFINAE over builtin operand type (short8 vs bf16x8) ----
template <typename A>
__device__ __forceinline__ auto mfma_sel(A a, A b, f32x4 c, int)
    -> decltype(__builtin_amdgcn_mfma_f32_16x16x32_bf16(a, b, c, 0, 0, 0)) {
  return __builtin_amdgcn_mfma_f32_16x16x32_bf16(a, b, c, 0, 0, 0);
}
template <typename A>
__device__ __forceinline__ auto mfma_sel(A a, A b, f32x4 c, long)
    -> decltype(__builtin_amdgcn_mfma_f32_16x16x32_bf16(
           __builtin_bit_cast(bf16x8, a), __builtin_bit_cast(bf16x8, b), c, 0, 0, 0)) {
  return __builtin_amdgcn_mfma_f32_16x16x32_bf16(
      __builtin_bit_cast(bf16x8, a), __builtin_bit_cast(bf16x8, b), c, 0, 0, 0);
}
__device__ __forceinline__ f32x4 MFMA16(short8 a, short8 b, f32x4 c) {
  return mfma_sel(a, b, c, 0);
}

__device__ __forceinline__ void gload16(const void* g, void* l) {
  __builtin_amdgcn_global_load_lds((const AS1 void*)g, (AS3 void*)l, 16, 0, 0);
}

// T1: bijective XCD-aware block swizzle (m204).
__device__ __forceinline__ int swz_bid(int nwg) {
  int orig = (int)blockIdx.x;
  int xcd = orig & 7;
  int q = nwg >> 3, r = nwg & 7;
  int base = (xcd < r) ? xcd * (q + 1) : r * (q + 1) + (xcd - r) * q;
  return base + (orig >> 3);
}

// ---- build the 256x256 highpass operator, bf16, symmetric ----
__global__ __launch_bounds__(256) void build_M(unsigned short* __restrict__ Mb) {
  __shared__ float Cs[16], Ss[16];
  int t = threadIdx.x;
  if (t < 16) {
    float c = 0.f;
    for (int k = -4; k <= 3; ++k) c += cosf(0.39269908169872414f * (float)(k * t));
    Cs[t] = c;
    Ss[t] = -sinf(1.5707963267948966f * (float)t);
  }
  __syncthreads();
  int r = t >> 4, cc = t & 15;
  for (int j = 0; j < 256; ++j) {
    int dr = (r - (j >> 4)) & 15;
    int dc = (cc - (j & 15)) & 15;
    float val = ((t == j) ? 1.f : 0.f) - (Cs[dr] * Cs[dc] - Ss[dr] * Ss[dc]) * 0.00390625f;
    Mb[t * 256 + j] = f2bf(val);
  }
}

// ---- fused cast: x (NTOK*HIDD) -> xb, then all weights -> wqkvb||w1b||w2b ----
#define NX4     4816896         // NTOK*HIDD/4
#define WQ_END  589824          // 768*768
#define WK_END  1179648
#define WV_END  1769472
#define W1_END  4128768         // + 3072*768
#define WT_END  6488064         // + 3072*768
#define TOT4    (NX4 + WT_END / 4)
__global__ __launch_bounds__(256) void cast_all(const float* __restrict__ x,
                                                const float* __restrict__ qw,
                                                const float* __restrict__ kw,
                                                const float* __restrict__ vw,
                                                const float* __restrict__ w1,
                                                const float* __restrict__ w2,
                                                unsigned short* __restrict__ xb,
                                                unsigned short* __restrict__ wd) {
  for (long c = (long)blockIdx.x * 256 + threadIdx.x; c < TOT4;
       c += (long)gridDim.x * 256) {
    const float* s;
    unsigned short* d;
    long off;
    if (c < NX4) {
      s = x; d = xb; off = c * 4;
    } else {
      long i = (c - NX4) * 4;
      d = wd + i;
      if (i < WQ_END)       { s = qw; off = i; }
      else if (i < WK_END)  { s = kw; off = i - WQ_END; }
      else if (i < WV_END)  { s = vw; off = i - WK_END; }
      else if (i < W1_END)  { s = w1; off = i - WV_END; }
      else                  { s = w2; off = i - W1_END; }
      fl4 v = *(const fl4*)(s + off);
      us4 o;
      o[0] = f2bf(v[0]); o[1] = f2bf(v[1]); o[2] = f2bf(v[2]); o[3] = f2bf(v[3]);
      *(us4*)d = o;
      continue;
    }
    fl4 v = *(const fl4*)(s + off);
    us4 o;
    o[0] = f2bf(v[0]); o[1] = f2bf(v[1]); o[2] = f2bf(v[2]); o[3] = f2bf(v[3]);
    *(us4*)(d + off) = o;
  }
}

// ---- concat q_b,k_b,v_b -> [2304] fp32 ----
__global__ __launch_bounds__(256) void bias_cat(const float* __restrict__ qb,
                                                const float* __restrict__ kb,
                                                const float* __restrict__ vb,
                                                float* __restrict__ d) {
  for (int i = threadIdx.x; i < QKVS; i += 256)
    d[i] = (i < 768) ? qb[i] : (i < 1536) ? kb[i - 768] : vb[i - 1536];
}

// ---- 256x256x64 GEMM v3: A triple-buffer, B single-buffer, 4 phases/tile,
// one counted vmcnt per tile. LDS A0/A1/A2/B = 128KB. Kdim % 384 == 0.
template <int OUT_BF16, int BIAS, int RELU>
__global__ __launch_bounds__(512, 2) void gemm256(const unsigned short* __restrict__ A,
                                                  const unsigned short* __restrict__ Bm,
                                                  const float* __restrict__ bias,
                                                  void* __restrict__ Cp,
                                                  int Mdim, int Ndim, int Kdim) {
  __shared__ __align__(16) char lds[131072];
  const int nbn = Ndim >> 8;
  const int bid = swz_bid((int)gridDim.x);
  const int bm = bid / nbn, bn = bid % nbn;
  const int t = threadIdx.x;
  const int lane = t & 63, w = t >> 6;
  const int wm = w >> 2, wn = w & 3;
  const int lm = lane & 15, lg = lane >> 4;
  const int NT = Kdim >> 6;          // K-tiles of 64; NT % 6 == 0

  const int tr = t >> 3;
  const int scol = ((t & 7) ^ (tr & 7)) * 8;
  const unsigned short* Asrc = A + (size_t)(bm * 256 + tr) * Kdim + scol;
  const unsigned short* Bsrc = Bm + (size_t)(bn * 256 + tr) * Kdim + scol;
  const size_t K64 = (size_t)64 * Kdim, K128 = (size_t)128 * Kdim, K192 = (size_t)192 * Kdim;

  char* const A0 = lds;
  char* const A1 = lds + 32768;
  char* const A2 = lds + 65536;
  char* const Bb = lds + 98304;

  auto SA = [&](int kt, char* abuf) {
    const unsigned short* s = Asrc + kt * 64;
    gload16(s, abuf + t * 16);
    gload16(s + K64, abuf + 8192 + t * 16);
    gload16(s + K128, abuf + 16384 + t * 16);
    gload16(s + K192, abuf + 24576 + t * 16);
  };
  auto SB = [&](int kt) {
    const unsigned short* s = Bsrc + kt * 64;
    gload16(s, Bb + t * 16);
    gload16(s + K64, Bb + 8192 + t * 16);
    gload16(s + K128, Bb + 16384 + t * 16);
    gload16(s + K192, Bb + 24576 + t * 16);
  };

  const int sx = lm & 7;
  int slotb[2];
#pragma unroll
  for (int kk = 0; kk < 2; ++kk) slotb[kk] = (((kk << 2) | lg) ^ sx) << 4;
  const int aoff = wm * 16384 + lm * 128;
  const int boff = (wn >> 1) * 16384 + ((wn & 1) * 64 + lm) * 128;

  f32x4 acc[8][4];
#pragma unroll
  for (int i = 0; i < 8; ++i)
#pragma unroll
    for (int j = 0; j < 4; ++j) acc[i][j] = (f32x4){0.f, 0.f, 0.f, 0.f};
  short8 bqA[4][2], bqB[4][2];

  auto RDB = [&](short8 (&bq)[4][2]) {
#pragma unroll
    for (int ni = 0; ni < 4; ++ni)
#pragma unroll
      for (int kk = 0; kk < 2; ++kk)
        bq[ni][kk] = *(const short8*)(Bb + boff + ni * 2048 + slotb[kk]);
  };
  auto PH = [&](const char* abuf, int q, short8 (&bq)[4][2], int vmc) {
    short8 aq[2][2];
#pragma unroll
    for (int m2 = 0; m2 < 2; ++m2)
#pragma unroll
      for (int kk = 0; kk < 2; ++kk)
        aq[m2][kk] = *(const short8*)(abuf + aoff + q * 4096 + m2 * 2048 + slotb[kk]);
    __builtin_amdgcn_s_barrier();
    asm volatile("s_waitcnt lgkmcnt(0)" ::: "memory");
    __builtin_amdgcn_sched_barrier(0);
    __builtin_amdgcn_s_setprio(1);
#pragma unroll
    for (int kk = 0; kk < 2; ++kk)
#pragma unroll
      for (int m2 = 0; m2 < 2; ++m2)
#pragma unroll
        for (int ni = 0; ni < 4; ++ni)
          acc[q * 2 + m2][ni] = MFMA16(aq[m2][kk], bq[ni][kk], acc[q * 2 + m2][ni]);
    __builtin_amdgcn_s_setprio(0);
    if (vmc == 4)      asm volatile("s_waitcnt vmcnt(4)" ::: "memory");
    else if (vmc == 0) asm volatile("s_waitcnt vmcnt(0)" ::: "memory");
    __builtin_amdgcn_s_barrier();
    __builtin_amdgcn_sched_barrier(0);
  };

  auto TILE = [&](int i, char* curA, char* nxtA, short8 (&cur)[4][2], short8 (&nxt)[4][2]) {
    const bool h1 = (i + 1 < NT), h2 = (i + 2 < NT);
    if (h1) SB(i + 1);
    if (h2) SA(i + 2, nxtA);
    PH(curA, 0, cur, -1);                              // P1
    PH(curA, 1, cur, -1);                              // P2
    PH(curA, 2, cur, h2 ? 4 : (h1 ? 0 : -1));          // P3 (the one wait)
    if (h1) RDB(nxt);
    PH(curA, 3, cur, -1);                              // P4
  };

  SA(0, A0); SB(0); SA(1, A1);
  asm volatile("s_waitcnt vmcnt(4)" ::: "memory");
  __builtin_amdgcn_s_barrier();
  __builtin_amdgcn_sched_barrier(0);
  RDB(bqA);
  asm volatile("s_waitcnt lgkmcnt(0)" ::: "memory");
  __builtin_amdgcn_sched_barrier(0);
  __builtin_amdgcn_s_barrier();
  __builtin_amdgcn_sched_barrier(0);

  for (int J = 0; J < NT / 6; ++J) {
    const int b6 = J * 6;
    TILE(b6 + 0, A0, A2, bqA, bqB);
    TILE(b6 + 1, A1, A0, bqB, bqA);
    TILE(b6 + 2, A2, A1, bqA, bqB);
    TILE(b6 + 3, A0, A2, bqB, bqA);
    TILE(b6 + 4, A1, A0, bqA, bqB);
    TILE(b6 + 5, A2, A1, bqB, bqA);
  }

  const int row0 = bm * 256 + wm * 128 + lg * 4;
  const int col0 = bn * 256 + wn * 64 + lm;
#pragma unroll
  for (int mi = 0; mi < 8; ++mi) {
#pragma unroll
    for (int ni = 0; ni < 4; ++ni) {
      int col = col0 + ni * 16;
      float bia = BIAS ? bias[col] : 0.f;
#pragma unroll
      for (int rg = 0; rg < 4; ++rg) {
        int row = row0 + mi * 16 + rg;
        float vv = acc[mi][ni][rg] + bia;
        if (RELU) vv = vv > 0.f ? vv : 0.f;
        if (OUT_BF16)
          ((unsigned short*)Cp)[(size_t)row * Ndim + col] = f2bf(vv);
        else
          ((float*)Cp)[(size_t)row * Ndim + col] = vv;
      }
    }
  }
}

// ---- 128x128x64 GEMM, 8-phase schedule, 64KB LDS -> 2 blocks/CU ----
template <int OUT_BF16, int BIAS, int RELU>
__global__ __launch_bounds__(512, 4) void gemm128(const unsigned short* __restrict__ A,
                                                  const unsigned short* __restrict__ Bm,
                                                  const float* __restrict__ bias,
                                                  void* __restrict__ Cp,
                                                  int Mdim, int Ndim, int Kdim) {
  __shared__ __align__(16) char lds[65536];
  const int nbn = Ndim >> 7;
  const int bid = swz_bid((int)gridDim.x);
  const int bm = bid / nbn, bn = bid % nbn;
  const int t = threadIdx.x;
  const int lane = t & 63, w = t >> 6;
  const int wm = w >> 2, wn = w & 3;
  const int lm = lane & 15, lg = lane >> 4;
  const int NITER = Kdim >> 7;   // K-tiles of 64, 2 per iter

  const int tr = t >> 3;
  const int scol = ((t & 7) ^ (tr & 7)) * 8;
  const unsigned short* Asrc = A + (size_t)(bm * 128 + tr) * Kdim + scol;
  const unsigned short* Bsrc = Bm + (size_t)(bn * 128 + tr) * Kdim + scol;
  const size_t K64 = (size_t)64 * Kdim;

  char* const d0 = lds;
  char* const d1 = lds + 32768;

  auto SA = [&](int kt, int d) {
    char* dst = lds + d * 32768;
    const unsigned short* s = Asrc + kt * 64;
    gload16(s, dst + t * 16);
    gload16(s + K64, dst + 8192 + t * 16);
  };
  auto SB = [&](int kt, int d, int h) {
    char* dst = lds + d * 32768 + 16384 + h * 8192;
    gload16(Bsrc + kt * 64 + (h ? K64 : 0), dst + t * 16);
  };

  const int sx = lm & 7;
  int slotb[2];
#pragma unroll
  for (int kk = 0; kk < 2; ++kk) slotb[kk] = (((kk << 2) | lg) ^ sx) << 4;
  const int aoff = (wm * 64 + lm) * 128;
  const int boff = 16384 + (wn * 32 + lm) * 128;

  f32x4 acc[4][2];
#pragma unroll
  for (int i = 0; i < 4; ++i)
#pragma unroll
    for (int j = 0; j < 2; ++j) acc[i][j] = (f32x4){0.f, 0.f, 0.f, 0.f};
  short8 bqA[2][2], bqB[2][2];

  auto RDB = [&](const char* db, short8 (&bq)[2][2]) {
#pragma unroll
    for (int ni = 0; ni < 2; ++ni)
#pragma unroll
      for (int kk = 0; kk < 2; ++kk)
        bq[ni][kk] = *(const short8*)(db + boff + ni * 2048 + slotb[kk]);
  };
  auto PH = [&](const char* db, int q, short8 (&bq)[2][2], int vmc) {
    short8 aq[2];
#pragma unroll
    for (int kk = 0; kk < 2; ++kk)
      aq[kk] = *(const short8*)(db + aoff + q * 2048 + slotb[kk]);
    __builtin_amdgcn_s_barrier();
    asm volatile("s_waitcnt lgkmcnt(0)" ::: "memory");
    __builtin_amdgcn_sched_barrier(0);
    __builtin_amdgcn_s_setprio(1);
#pragma unroll
    for (int kk = 0; kk < 2; ++kk)
#pragma unroll
      for (int ni = 0; ni < 2; ++ni)
        acc[q][ni] = MFMA16(aq[kk], bq[ni][kk], acc[q][ni]);
    __builtin_amdgcn_s_setprio(0);
    if (vmc == 4)      asm volatile("s_waitcnt vmcnt(4)" ::: "memory");
    else if (vmc == 2) asm volatile("s_waitcnt vmcnt(2)" ::: "memory");
    else if (vmc == 0) asm volatile("s_waitcnt vmcnt(0)" ::: "memory");
    __builtin_amdgcn_s_barrier();
    __builtin_amdgcn_sched_barrier(0);
  };

  SA(0, 0); SB(0, 0, 0); SB(0, 0, 1); SB(1, 1, 0); SB(1, 1, 1);
  asm volatile("s_waitcnt vmcnt(2)" ::: "memory");
  __builtin_amdgcn_s_barrier();
  __builtin_amdgcn_sched_barrier(0);
  RDB(d0, bqA);

  for (int j = 0; j < NITER; ++j) {
    const bool nl = (j + 1 < NITER);
    const int t2 = 2 * j + 2, t3 = 2 * j + 3;
    SA(2 * j + 1, 1);       PH(d0, 0, bqA, -1);
    if (nl) SB(t2, 0, 0);   PH(d0, 1, bqA, -1);
    if (nl) SB(t2, 0, 1);   PH(d0, 2, bqA, nl ? 4 : 2);
    RDB(d1, bqB);           PH(d0, 3, bqA, nl ? 2 : 0);
    if (nl) SA(t2, 0);      PH(d1, 0, bqB, -1);
    if (nl) SB(t3, 1, 0);   PH(d1, 1, bqB, -1);
    if (nl) SB(t3, 1, 1);   PH(d1, 2, bqB, nl ? 4 : -1);
    if (nl) RDB(d0, bqA);   PH(d1, 3, bqB, nl ? 2 : -1);
  }

  const int row0 = bm * 128 + wm * 64 + lg * 4;
  const int col0 = bn * 128 + wn * 32 + lm;
#pragma unroll
  for (int mi = 0; mi < 4; ++mi) {
#pragma unroll
    for (int ni = 0; ni < 2; ++ni) {
      int col = col0 + ni * 16;
      float bia = BIAS ? bias[col] : 0.f;
#pragma unroll
      for (int rg = 0; rg < 4; ++rg) {
        int row = row0 + mi * 16 + rg;
        float vv = acc[mi][ni][rg] + bia;
        if (RELU) vv = vv > 0.f ? vv : 0.f;
        if (OUT_BF16)
          ((unsigned short*)Cp)[(size_t)row * Ndim + col] = f2bf(vv);
        else
          ((float*)Cp)[(size_t)row * Ndim + col] = vv;
      }
    }
  }
}

// ---- LN kernels: 512 threads, 8 rows per block ----
__global__ __launch_bounds__(512) void ln0_k(const unsigned short* __restrict__ x,
                                             const float* __restrict__ g,
                                             const float* __restrict__ bb,
                                             unsigned short* __restrict__ out) {
  int w = threadIdx.x >> 6, lane = threadIdx.x & 63;
  long row = (long)blockIdx.x * 8 + w;
  const unsigned short* xr = x + row * HIDD;
  float xv[12];
  float s1 = 0.f, s2 = 0.f;
#pragma unroll
  for (int c = 0; c < 3; ++c) {
    us4 u = *(const us4*)(xr + c * 256 + lane * 4);
#pragma unroll
    for (int j = 0; j < 4; ++j) {
      float f = bf2f(u[j]);
      xv[c * 4 + j] = f; s1 += f; s2 += f * f;
    }
  }
#pragma unroll
  for (int off = 32; off; off >>= 1) { s1 += __shfl_xor(s1, off); s2 += __shfl_xor(s2, off); }
  float m = s1 * (1.f / 768.f);
  float rs = rsqrtf(s2 * (1.f / 768.f) - m * m + 1e-5f);
#pragma unroll
  for (int c = 0; c < 3; ++c) {
    int cb = c * 256 + lane * 4;
    us4 o;
#pragma unroll
    for (int j = 0; j < 4; ++j) o[j] = f2bf((xv[c * 4 + j] - m) * rs * g[cb + j] + bb[cb + j]);
    *(us4*)(out + row * HIDD + cb) = o;
  }
}

__global__ __launch_bounds__(512) void ln1_k(const unsigned short* __restrict__ ctx,
                                             const unsigned short* __restrict__ hp,
                                             const float* __restrict__ g,
                                             const float* __restrict__ bb,
                                             unsigned short* __restrict__ h2b) {
  int w = threadIdx.x >> 6, lane = threadIdx.x & 63;
  long row = (long)blockIdx.x * 8 + w;
  const unsigned short* xr = ctx + row * HIDD;
  float xv[12];
  float s1 = 0.f, s2 = 0.f;
#pragma unroll
  for (int c = 0; c < 3; ++c) {
    us4 u = *(const us4*)(xr + c * 256 + lane * 4);
#pragma unroll
    for (int j = 0; j < 4; ++j) {
      float f = bf2f(u[j]);
      xv[c * 4 + j] = f; s1 += f; s2 += f * f;
    }
  }
#pragma unroll
  for (int off = 32; off; off >>= 1) { s1 += __shfl_xor(s1, off); s2 += __shfl_xor(s2, off); }
  float m = s1 * (1.f / 768.f);
  float rs = rsqrtf(s2 * (1.f / 768.f) - m * m + 1e-5f);
#pragma unroll
  for (int c = 0; c < 3; ++c) {
    int cb = c * 256 + lane * 4;
    us4 hv = *(const us4*)(hp + row * HIDD + cb);
    us4 ob;
#pragma unroll
    for (int j = 0; j < 4; ++j)
      ob[j] = f2bf(bf2f(hv[j]) + (xv[c * 4 + j] - m) * rs * g[cb + j] + bb[cb + j]);
    *(us4*)(h2b + row * HIDD + cb) = ob;
  }
}

// ln2: out_fp32 = h2(bf16) + LN(mlp2 bf16)
__global__ __launch_bounds__(512) void ln2_k(const unsigned short* __restrict__ m2b,
                                             const unsigned short* __restrict__ h2b,
                                             const float* __restrict__ g,
                                             const float* __restrict__ bb,
                                             float* __restrict__ outp) {
  int w = threadIdx.x >> 6, lane = threadIdx.x & 63;
  long row = (long)blockIdx.x * 8 + w;
  const unsigned short* xr = m2b + row * HIDD;
  float xv[12];
  float s1 = 0.f, s2 = 0.f;
#pragma unroll
  for (int c = 0; c < 3; ++c) {
    us4 u = *(const us4*)(xr + c * 256 + lane * 4);
#pragma unroll
    for (int j = 0; j < 4; ++j) {
      float f = bf2f(u[j]);
      xv[c * 4 + j] = f; s1 += f; s2 += f * f;
    }
  }
#pragma unroll
  for (int off = 32; off; off >>= 1) { s1 += __shfl_xor(s1, off); s2 += __shfl_xor(s2, off); }
  float m = s1 * (1.f / 768.f);
  float rs = rsqrtf(s2 * (1.f / 768.f) - m * m + 1e-5f);
#pragma unroll
  for (int c = 0; c < 3; ++c) {
    int cb = c * 256 + lane * 4;
    us4 hv = *(const us4*)(h2b + row * HIDD + cb);
    fl4 o;
#pragma unroll
    for (int j = 0; j < 4; ++j)
      o[j] = bf2f(hv[j]) + (xv[c * 4 + j] - m) * rs * g[cb + j] + bb[cb + j];
    *(fl4*)(outp + row * HIDD + cb) = o;
  }
}

// ---- fused attention over interleaved qkv[tok][2304] ----
__global__ __launch_bounds__(256, 2) void attn_k(const unsigned short* __restrict__ qkv,
                                                 unsigned short* __restrict__ ctx) {
  __shared__ __align__(16) unsigned short Ks[NPAT * 64];
  __shared__ __align__(16) unsigned short VT[64 * 232];
  __shared__ __align__(16) unsigned short PL[4][16 * 40];
  const int b = blockIdx.x / NHEAD, h = blockIdx.x % NHEAD;
  const int t = threadIdx.x, lane = t & 63, w = t >> 6;
  const size_t base = ((size_t)b * NPAT) * QKVS + h * HDIM;

  for (int idx = t; idx < NPAT * 8; idx += 256) {
    int row = idx >> 3, s = idx & 7;
    us8 kv = *(const us8*)&qkv[base + 768 + (size_t)row * QKVS + s * 8];
    *(us8*)((char*)Ks + row * 128 + ((s ^ (row & 7)) << 4)) = kv;
  }
  for (int idx = t; idx < 98 * 64; idx += 256) {
    int pp = idx >> 6, d = idx & 63;
    unsigned int val = (unsigned int)qkv[base + 1536 + (size_t)(2 * pp) * QKVS + d]
                     | ((unsigned int)qkv[base + 1536 + (size_t)(2 * pp + 1) * QKVS + d] << 16);
    *(unsigned int*)&VT[d * 232 + 2 * pp] = val;
  }
  for (int idx = t; idx < 64 * 18; idx += 256) {
    int d = idx / 18, c = idx % 18;
    *(unsigned int*)&VT[d * 232 + 196 + 2 * c] = 0;
  }
  __syncthreads();

  unsigned short* plw = (unsigned short*)PL[w];
  const int lm = lane & 15, lg = lane >> 4, lk = lg * 8;

  for (int qt = w; qt < 13; qt += 4) {
    const int q0 = qt * 16;
    int qrow = q0 + lm; if (qrow > NPAT - 1) qrow = NPAT - 1;
    short8 af0 = *(const short8*)&qkv[base + (size_t)qrow * QKVS + lk];
    short8 af1 = *(const short8*)&qkv[base + (size_t)qrow * QKVS + 32 + lk];

    f32x4 sc[13];
#pragma unroll
    for (int kt = 0; kt < 13; ++kt) {
      int krow = kt * 16 + lm; if (krow > NPAT - 1) krow = NPAT - 1;
      const char* krp = (const char*)Ks + krow * 128;
      short8 b0 = *(const short8*)(krp + (((lg ^ (krow & 7)) & 7) << 4));
      short8 b1 = *(const short8*)(krp + ((((lg + 4) ^ (krow & 7)) & 7) << 4));
      f32x4 z = (f32x4){0.f, 0.f, 0.f, 0.f};
      z = MFMA16(af0, b0, z);
      sc[kt] = MFMA16(af1, b1, z);
    }
#pragma unroll
    for (int kt = 0; kt < 13; ++kt) {
      int col = kt * 16 + lm;
#pragma unroll
      for (int rg = 0; rg < 4; ++rg) {
        float s = sc[kt][rg] * 0.125f;
        sc[kt][rg] = (col < NPAT) ? s : -1e30f;
      }
    }
    float inv[4];
#pragma unroll
    for (int rg = 0; rg < 4; ++rg) {
      float m = -1e30f;
#pragma unroll
      for (int kt = 0; kt < 13; ++kt) m = fmaxf(m, sc[kt][rg]);
      m = fmaxf(m, __shfl_xor(m, 1)); m = fmaxf(m, __shfl_xor(m, 2));
      m = fmaxf(m, __shfl_xor(m, 4)); m = fmaxf(m, __shfl_xor(m, 8));
      float s = 0.f;
#pragma unroll
      for (int kt = 0; kt < 13; ++kt) { float e = __expf(sc[kt][rg] - m); sc[kt][rg] = e; s += e; }
      s += __shfl_xor(s, 1); s += __shfl_xor(s, 2); s += __shfl_xor(s, 4); s += __shfl_xor(s, 8);
      inv[rg] = 1.f / s;
    }

    f32x4 oacc[4];
#pragma unroll
    for (int ni = 0; ni < 4; ++ni) oacc[ni] = (f32x4){0.f, 0.f, 0.f, 0.f};
#pragma unroll
    for (int kc = 0; kc < 7; ++kc) {
#pragma unroll
      for (int sub = 0; sub < 2; ++sub) {
        const int kt = 2 * kc + sub;
#pragma unroll
        for (int rg = 0; rg < 4; ++rg) {
          unsigned short pv_ = 0;
          if (kt < 13) pv_ = f2bf(sc[kt][rg] * inv[rg]);
          plw[(lg * 4 + rg) * 40 + sub * 16 + lm] = pv_;
        }
      }
      asm volatile("s_waitcnt lgkmcnt(0)" ::: "memory");
      __builtin_amdgcn_sched_barrier(0);
      short8 pa = *(const short8*)&plw[lm * 40 + lk];
#pragma unroll
      for (int ni = 0; ni < 4; ++ni) {
        short8 bv = *(const short8*)&VT[(ni * 16 + lm) * 232 + kc * 32 + lk];
        oacc[ni] = MFMA16(pa, bv, oacc[ni]);
      }
    }
#pragma unroll
    for (int rg = 0; rg < 4; ++rg) {
      int r = q0 + lg * 4 + rg;
      if (r < NPAT) {
#pragma unroll
        for (int ni = 0; ni < 4; ++ni)
          ctx[((size_t)b * NPAT + r) * HIDD + h * HDIM + ni * 16 + lm] = f2bf(oacc[ni][rg]);
      }
    }
  }
}

extern "C" void kernel_launch(void* const* d_in, const int* in_sizes, int n_in,
                              void* d_out, int out_size, void* d_ws, size_t ws_size,
                              hipStream_t stream) {
  const float* x    = (const float*)d_in[0];
  const float* q_w  = (const float*)d_in[1];
  const float* q_b  = (const float*)d_in[2];
  const float* k_w  = (const float*)d_in[3];
  const float* k_b  = (const float*)d_in[4];
  const float* v_w  = (const float*)d_in[5];
  const float* v_b  = (const float*)d_in[6];
  const float* w1   = (const float*)d_in[7];
  const float* b1   = (const float*)d_in[8];
  const float* w2   = (const float*)d_in[9];
  const float* b2   = (const float*)d_in[10];
  const float* ln0g = (const float*)d_in[11];
  const float* ln0b = (const float*)d_in[12];
  const float* ln1g = (const float*)d_in[13];
  const float* ln1b = (const float*)d_in[14];
  const float* ln2g = (const float*)d_in[15];
  const float* ln2b = (const float*)d_in[16];

  char* ws = (char*)d_ws;
  size_t o = 0;
  auto alloc = [&](size_t bytes) { size_t r = o; o += (bytes + 255) & ~(size_t)255; return r; };

  const size_t RSZ = (size_t)NTOK * HIDD * 2;
  unsigned short* Mb    = (unsigned short*)(ws + alloc(256 * 256 * 2));
  unsigned short* wqkvb = (unsigned short*)(ws + alloc((size_t)QKVS * HIDD * 2));
  unsigned short* w1b   = (unsigned short*)(ws + alloc((size_t)FFD * HIDD * 2));
  unsigned short* w2b   = (unsigned short*)(ws + alloc((size_t)HIDD * FFD * 2));
  float*          qkvbias = (float*)(ws + alloc(QKVS * 4));
  char* rA  = ws + alloc(RSZ);   // hp bf16 -> mlp2 bf16
  char* rB  = ws + alloc(RSZ);   // hb (ln0 out) -> h2 bf16
  char* rC0 = ws + alloc(RSZ);   // x bf16 -> ctx -> mlp1[0:RSZ]
  char* rC1 = ws + alloc(RSZ);   // qkv low   -> mlp1[RSZ:2RSZ]
  char* rC2 = ws + alloc(RSZ);   // qkv mid
  char* rC3 = ws + alloc(RSZ);   // qkv high
  (void)rC2; (void)rC3; (void)n_in; (void)in_sizes; (void)ws_size;

  unsigned short* xb  = (unsigned short*)rC0;
  unsigned short* hpb = (unsigned short*)rA;
  unsigned short* hb  = (unsigned short*)rB;
  unsigned short* qkv = (unsigned short*)rC1;  // [25088][2304] spans rC1..rC3
  unsigned short* cxb = (unsigned short*)rC0;  // ctx (x dead after highpass)
  unsigned short* h2b = (unsigned short*)rB;   // hb dead after QKV
  unsigned short* m1b = (unsigned short*)rC0;  // mlp1 full: 154MB spans rC0..rC3
  unsigned short* m2b = (unsigned short*)rA;   // mlp2 bf16 (hp dead after ln1)

  build_M<<<1, 256, 0, stream>>>(Mb);
  bias_cat<<<1, 256, 0, stream>>>(q_b, k_b, v_b, qkvbias);

  // fused cast: x -> xb, and all weights -> contiguous wqkvb||w1b||w2b
  cast_all<<<2048, 256, 0, stream>>>(x, q_w, k_w, v_w, w1, w2, xb, wqkvb);

  // highpass: (75264 x 256) @ M^T via gemm128: 1176 blocks, 2/CU
  gemm128<1, 0, 0><<<588 * 2, 512, 0, stream>>>(xb, Mb, nullptr, hpb, 75264, 256, 256);
  ln0_k<<<NTOK / 8, 512, 0, stream>>>(hpb, ln0g, ln0b, hb);

  // fused QKV: gemm256 v3, 98 x 9 = 882 blocks, K=768 (NT=12)
  gemm256<1, 1, 0><<<98 * 9, 512, 0, stream>>>(hb, wqkvb, qkvbias, qkv, NTOK, QKVS, HIDD);

  attn_k<<<128 * NHEAD, 256, 0, stream>>>(qkv, cxb);

  ln1_k<<<NTOK / 8, 512, 0, stream>>>(cxb, hpb, ln1g, ln1b, h2b);

  // mlp1: gemm256 v3, 98 x 12 = 1176 blocks, K=768 (NT=12)
  gemm256<1, 1, 1><<<98 * 12, 512, 0, stream>>>(h2b, w1b, b1, m1b, NTOK, FFD, HIDD);
  // mlp2: gemm128, bf16 out -> rA: 196 x 6 = 1176 blocks, 2/CU, K=3072
  gemm128<1, 1, 0><<<196 * 6, 512, 0, stream>>>(m1b, w2b, b2, m2b, NTOK, HIDD, FFD);

  // final: d_out = h2 + LN(mlp2), fp32 straight out
  ln2_k<<<NTOK / 8, 512, 0, stream>>>(m2b, h2b, ln2g, ln2b, (float*)d_out);
  (void)out_size;
}

// Round 17
// 581.574 us; speedup vs baseline: 1.0253x; 1.0253x over previous
//
#include <hip/hip_runtime.h>

#define NTOK   25088          // B*P = 128*196
#define HIDD   768
#define NHEAD  12
#define HDIM   64
#define FFD    3072
#define NPAT   196
#define QKVS   2304           // interleaved qkv row stride

typedef __attribute__((ext_vector_type(8))) short short8;
typedef __attribute__((ext_vector_type(8))) __bf16 bf16x8;
typedef __attribute__((ext_vector_type(4))) float f32x4;
typedef __attribute__((ext_vector_type(4))) float fl4;
typedef __attribute__((ext_vector_type(4))) unsigned short us4;
typedef __attribute__((ext_vector_type(8))) unsigned short us8;

#define AS1 __attribute__((address_space(1)))
#define AS3 __attribute__((address_space(3)))

__device__ __forceinline__ unsigned short f2bf(float f) {
  unsigned int u = __builtin_bit_cast(unsigned int, f);
  u += 0x7FFFu + ((u >> 16) & 1u);
  return (unsigned short)(u >> 16);
}
__device__ __forceinline__ float bf2f(unsigned short h) {
  unsigned int u = ((unsigned int)h) << 16;
  return __builtin_bit_cast(float, u);
}

// ---- MFMA wrapper: SFINAE over builtin operand type (short8 vs bf16x8) ----
template <typename A>
__device__ __forceinline__ auto mfma_sel(A a, A b, f32x4 c, int)
    -> decltype(__builtin_amdgcn_mfma_f32_16x16x32_bf16(a, b, c, 0, 0, 0)) {
  return __builtin_amdgcn_mfma_f32_16x16x32_bf16(a, b, c, 0, 0, 0);
}
template <typename A>
__device__ __forceinline__ auto mfma_sel(A a, A b, f32x4 c, long)
    -> decltype(__builtin_amdgcn_mfma_f32_16x16x32_bf16(
           __builtin_bit_cast(bf16x8, a), __builtin_bit_cast(bf16x8, b), c, 0, 0, 0)) {
  return __builtin_amdgcn_mfma_f32_16x16x32_bf16(
      __builtin_bit_cast(bf16x8, a), __builtin_bit_cast(bf16x8, b), c, 0, 0, 0);
}
__device__ __forceinline__ f32x4 MFMA16(short8 a, short8 b, f32x4 c) {
  return mfma_sel(a, b, c, 0);
}

__device__ __forceinline__ void gload16(const void* g, void* l) {
  __builtin_amdgcn_global_load_lds((const AS1 void*)g, (AS3 void*)l, 16, 0, 0);
}

// T1: bijective XCD-aware block swizzle (m204).
__device__ __forceinline__ int swz_bid(int nwg) {
  int orig = (int)blockIdx.x;
  int xcd = orig & 7;
  int q = nwg >> 3, r = nwg & 7;
  int base = (xcd < r) ? xcd * (q + 1) : r * (q + 1) + (xcd - r) * q;
  return base + (orig >> 3);
}

// ---- fused prologue: block 0 builds the 256x256 highpass operator (bf16),
// block 1 concats q_b,k_b,v_b -> [2304] fp32 ----
__global__ __launch_bounds__(256) void prep_k(const float* __restrict__ qb,
                                              const float* __restrict__ kb,
                                              const float* __restrict__ vb,
                                              float* __restrict__ biasd,
                                              unsigned short* __restrict__ Mb) {
  if (blockIdx.x == 0) {
    __shared__ float Cs[16], Ss[16];
    int t = threadIdx.x;
    if (t < 16) {
      float c = 0.f;
      for (int k = -4; k <= 3; ++k) c += cosf(0.39269908169872414f * (float)(k * t));
      Cs[t] = c;
      Ss[t] = -sinf(1.5707963267948966f * (float)t);
    }
    __syncthreads();
    int r = t >> 4, cc = t & 15;
    for (int j = 0; j < 256; ++j) {
      int dr = (r - (j >> 4)) & 15;
      int dc = (cc - (j & 15)) & 15;
      float val = ((t == j) ? 1.f : 0.f) - (Cs[dr] * Cs[dc] - Ss[dr] * Ss[dc]) * 0.00390625f;
      Mb[t * 256 + j] = f2bf(val);
    }
  } else {
    for (int i = threadIdx.x; i < QKVS; i += 256)
      biasd[i] = (i < 768) ? qb[i] : (i < 1536) ? kb[i - 768] : vb[i - 1536];
  }
}

// ---- fp32 -> bf16 cast (x only) ----
__global__ __launch_bounds__(256) void castk(const float* __restrict__ s,
                                             unsigned short* __restrict__ d, long n4) {
  for (long i = (long)blockIdx.x * 256 + threadIdx.x; i < n4; i += (long)gridDim.x * 256) {
    fl4 v = *(const fl4*)(s + i * 4);
    us4 o;
    o[0] = f2bf(v[0]); o[1] = f2bf(v[1]); o[2] = f2bf(v[2]); o[3] = f2bf(v[3]);
    *(us4*)(d + i * 4) = o;
  }
}

// ---- fused cast of all weights into contiguous wqkvb||w1b||w2b ----
#define WQ_END  589824          // 768*768
#define WK_END  1179648
#define WV_END  1769472
#define W1_END  4128768         // + 3072*768
#define WT_END  6488064         // + 3072*768
__global__ __launch_bounds__(256) void wcast(const float* __restrict__ qw,
                                             const float* __restrict__ kw,
                                             const float* __restrict__ vw,
                                             const float* __restrict__ w1,
                                             const float* __restrict__ w2,
                                             unsigned short* __restrict__ d) {
  for (long c = (long)blockIdx.x * 256 + threadIdx.x; c < WT_END / 4;
       c += (long)gridDim.x * 256) {
    long i = c * 4;
    const float* s; long off;
    if (i < WQ_END)       { s = qw; off = i; }
    else if (i < WK_END)  { s = kw; off = i - WQ_END; }
    else if (i < WV_END)  { s = vw; off = i - WK_END; }
    else if (i < W1_END)  { s = w1; off = i - WV_END; }
    else                  { s = w2; off = i - W1_END; }
    fl4 v = *(const fl4*)(s + off);
    us4 o;
    o[0] = f2bf(v[0]); o[1] = f2bf(v[1]); o[2] = f2bf(v[2]); o[3] = f2bf(v[3]);
    *(us4*)(d + i) = o;
  }
}

// ---- 256x256x64 GEMM v3: A triple-buffer, B single-buffer, 4 phases/tile,
// one counted vmcnt per tile. LDS A0/A1/A2/B = 128KB. Kdim % 384 == 0.
template <int OUT_BF16, int BIAS, int RELU>
__global__ __launch_bounds__(512, 2) void gemm256(const unsigned short* __restrict__ A,
                                                  const unsigned short* __restrict__ Bm,
                                                  const float* __restrict__ bias,
                                                  void* __restrict__ Cp,
                                                  int Mdim, int Ndim, int Kdim) {
  __shared__ __align__(16) char lds[131072];
  const int nbn = Ndim >> 8;
  const int bid = swz_bid((int)gridDim.x);
  const int bm = bid / nbn, bn = bid % nbn;
  const int t = threadIdx.x;
  const int lane = t & 63, w = t >> 6;
  const int wm = w >> 2, wn = w & 3;
  const int lm = lane & 15, lg = lane >> 4;
  const int NT = Kdim >> 6;          // K-tiles of 64; NT % 6 == 0

  const int tr = t >> 3;
  const int scol = ((t & 7) ^ (tr & 7)) * 8;
  const unsigned short* Asrc = A + (size_t)(bm * 256 + tr) * Kdim + scol;
  const unsigned short* Bsrc = Bm + (size_t)(bn * 256 + tr) * Kdim + scol;
  const size_t K64 = (size_t)64 * Kdim, K128 = (size_t)128 * Kdim, K192 = (size_t)192 * Kdim;

  char* const A0 = lds;
  char* const A1 = lds + 32768;
  char* const A2 = lds + 65536;
  char* const Bb = lds + 98304;

  auto SA = [&](int kt, char* abuf) {
    const unsigned short* s = Asrc + kt * 64;
    gload16(s, abuf + t * 16);
    gload16(s + K64, abuf + 8192 + t * 16);
    gload16(s + K128, abuf + 16384 + t * 16);
    gload16(s + K192, abuf + 24576 + t * 16);
  };
  auto SB = [&](int kt) {
    const unsigned short* s = Bsrc + kt * 64;
    gload16(s, Bb + t * 16);
    gload16(s + K64, Bb + 8192 + t * 16);
    gload16(s + K128, Bb + 16384 + t * 16);
    gload16(s + K192, Bb + 24576 + t * 16);
  };

  const int sx = lm & 7;
  int slotb[2];
#pragma unroll
  for (int kk = 0; kk < 2; ++kk) slotb[kk] = (((kk << 2) | lg) ^ sx) << 4;
  const int aoff = wm * 16384 + lm * 128;
  const int boff = (wn >> 1) * 16384 + ((wn & 1) * 64 + lm) * 128;

  f32x4 acc[8][4];
#pragma unroll
  for (int i = 0; i < 8; ++i)
#pragma unroll
    for (int j = 0; j < 4; ++j) acc[i][j] = (f32x4){0.f, 0.f, 0.f, 0.f};
  short8 bqA[4][2], bqB[4][2];

  auto RDB = [&](short8 (&bq)[4][2]) {
#pragma unroll
    for (int ni = 0; ni < 4; ++ni)
#pragma unroll
      for (int kk = 0; kk < 2; ++kk)
        bq[ni][kk] = *(const short8*)(Bb + boff + ni * 2048 + slotb[kk]);
  };
  auto PH = [&](const char* abuf, int q, short8 (&bq)[4][2], int vmc) {
    short8 aq[2][2];
#pragma unroll
    for (int m2 = 0; m2 < 2; ++m2)
#pragma unroll
      for (int kk = 0; kk < 2; ++kk)
        aq[m2][kk] = *(const short8*)(abuf + aoff + q * 4096 + m2 * 2048 + slotb[kk]);
    __builtin_amdgcn_s_barrier();
    asm volatile("s_waitcnt lgkmcnt(0)" ::: "memory");
    __builtin_amdgcn_sched_barrier(0);
    __builtin_amdgcn_s_setprio(1);
#pragma unroll
    for (int kk = 0; kk < 2; ++kk)
#pragma unroll
      for (int m2 = 0; m2 < 2; ++m2)
#pragma unroll
        for (int ni = 0; ni < 4; ++ni)
          acc[q * 2 + m2][ni] = MFMA16(aq[m2][kk], bq[ni][kk], acc[q * 2 + m2][ni]);
    __builtin_amdgcn_s_setprio(0);
    if (vmc == 4)      asm volatile("s_waitcnt vmcnt(4)" ::: "memory");
    else if (vmc == 0) asm volatile("s_waitcnt vmcnt(0)" ::: "memory");
    __builtin_amdgcn_s_barrier();
    __builtin_amdgcn_sched_barrier(0);
  };

  auto TILE = [&](int i, char* curA, char* nxtA, short8 (&cur)[4][2], short8 (&nxt)[4][2]) {
    const bool h1 = (i + 1 < NT), h2 = (i + 2 < NT);
    if (h1) SB(i + 1);
    if (h2) SA(i + 2, nxtA);
    PH(curA, 0, cur, -1);                              // P1
    PH(curA, 1, cur, -1);                              // P2
    PH(curA, 2, cur, h2 ? 4 : (h1 ? 0 : -1));          // P3 (the one wait)
    if (h1) RDB(nxt);
    PH(curA, 3, cur, -1);                              // P4
  };

  SA(0, A0); SB(0); SA(1, A1);
  asm volatile("s_waitcnt vmcnt(4)" ::: "memory");
  __builtin_amdgcn_s_barrier();
  __builtin_amdgcn_sched_barrier(0);
  RDB(bqA);
  asm volatile("s_waitcnt lgkmcnt(0)" ::: "memory");
  __builtin_amdgcn_sched_barrier(0);
  __builtin_amdgcn_s_barrier();
  __builtin_amdgcn_sched_barrier(0);

  for (int J = 0; J < NT / 6; ++J) {
    const int b6 = J * 6;
    TILE(b6 + 0, A0, A2, bqA, bqB);
    TILE(b6 + 1, A1, A0, bqB, bqA);
    TILE(b6 + 2, A2, A1, bqA, bqB);
    TILE(b6 + 3, A0, A2, bqB, bqA);
    TILE(b6 + 4, A1, A0, bqA, bqB);
    TILE(b6 + 5, A2, A1, bqB, bqA);
  }

  const int row0 = bm * 256 + wm * 128 + lg * 4;
  const int col0 = bn * 256 + wn * 64 + lm;
#pragma unroll
  for (int mi = 0; mi < 8; ++mi) {
#pragma unroll
    for (int ni = 0; ni < 4; ++ni) {
      int col = col0 + ni * 16;
      float bia = BIAS ? bias[col] : 0.f;
#pragma unroll
      for (int rg = 0; rg < 4; ++rg) {
        int row = row0 + mi * 16 + rg;
        float vv = acc[mi][ni][rg] + bia;
        if (RELU) vv = vv > 0.f ? vv : 0.f;
        if (OUT_BF16)
          ((unsigned short*)Cp)[(size_t)row * Ndim + col] = f2bf(vv);
        else
          ((float*)Cp)[(size_t)row * Ndim + col] = vv;
      }
    }
  }
}

// ---- 128x128x64 GEMM, 8-phase schedule, 64KB LDS -> 2 blocks/CU ----
template <int OUT_BF16, int BIAS, int RELU>
__global__ __launch_bounds__(512, 4) void gemm128(const unsigned short* __restrict__ A,
                                                  const unsigned short* __restrict__ Bm,
                                                  const float* __restrict__ bias,
                                                  void* __restrict__ Cp,
                                                  int Mdim, int Ndim, int Kdim) {
  __shared__ __align__(16) char lds[65536];
  const int nbn = Ndim >> 7;
  const int bid = swz_bid((int)gridDim.x);
  const int bm = bid / nbn, bn = bid % nbn;
  const int t = threadIdx.x;
  const int lane = t & 63, w = t >> 6;
  const int wm = w >> 2, wn = w & 3;
  const int lm = lane & 15, lg = lane >> 4;
  const int NITER = Kdim >> 7;   // K-tiles of 64, 2 per iter

  const int tr = t >> 3;
  const int scol = ((t & 7) ^ (tr & 7)) * 8;
  const unsigned short* Asrc = A + (size_t)(bm * 128 + tr) * Kdim + scol;
  const unsigned short* Bsrc = Bm + (size_t)(bn * 128 + tr) * Kdim + scol;
  const size_t K64 = (size_t)64 * Kdim;

  char* const d0 = lds;
  char* const d1 = lds + 32768;

  auto SA = [&](int kt, int d) {
    char* dst = lds + d * 32768;
    const unsigned short* s = Asrc + kt * 64;
    gload16(s, dst + t * 16);
    gload16(s + K64, dst + 8192 + t * 16);
  };
  auto SB = [&](int kt, int d, int h) {
    char* dst = lds + d * 32768 + 16384 + h * 8192;
    gload16(Bsrc + kt * 64 + (h ? K64 : 0), dst + t * 16);
  };

  const int sx = lm & 7;
  int slotb[2];
#pragma unroll
  for (int kk = 0; kk < 2; ++kk) slotb[kk] = (((kk << 2) | lg) ^ sx) << 4;
  const int aoff = (wm * 64 + lm) * 128;
  const int boff = 16384 + (wn * 32 + lm) * 128;

  f32x4 acc[4][2];
#pragma unroll
  for (int i = 0; i < 4; ++i)
#pragma unroll
    for (int j = 0; j < 2; ++j) acc[i][j] = (f32x4){0.f, 0.f, 0.f, 0.f};
  short8 bqA[2][2], bqB[2][2];

  auto RDB = [&](const char* db, short8 (&bq)[2][2]) {
#pragma unroll
    for (int ni = 0; ni < 2; ++ni)
#pragma unroll
      for (int kk = 0; kk < 2; ++kk)
        bq[ni][kk] = *(const short8*)(db + boff + ni * 2048 + slotb[kk]);
  };
  auto PH = [&](const char* db, int q, short8 (&bq)[2][2], int vmc) {
    short8 aq[2];
#pragma unroll
    for (int kk = 0; kk < 2; ++kk)
      aq[kk] = *(const short8*)(db + aoff + q * 2048 + slotb[kk]);
    __builtin_amdgcn_s_barrier();
    asm volatile("s_waitcnt lgkmcnt(0)" ::: "memory");
    __builtin_amdgcn_sched_barrier(0);
    __builtin_amdgcn_s_setprio(1);
#pragma unroll
    for (int kk = 0; kk < 2; ++kk)
#pragma unroll
      for (int ni = 0; ni < 2; ++ni)
        acc[q][ni] = MFMA16(aq[kk], bq[ni][kk], acc[q][ni]);
    __builtin_amdgcn_s_setprio(0);
    if (vmc == 4)      asm volatile("s_waitcnt vmcnt(4)" ::: "memory");
    else if (vmc == 2) asm volatile("s_waitcnt vmcnt(2)" ::: "memory");
    else if (vmc == 0) asm volatile("s_waitcnt vmcnt(0)" ::: "memory");
    __builtin_amdgcn_s_barrier();
    __builtin_amdgcn_sched_barrier(0);
  };

  SA(0, 0); SB(0, 0, 0); SB(0, 0, 1); SB(1, 1, 0); SB(1, 1, 1);
  asm volatile("s_waitcnt vmcnt(2)" ::: "memory");
  __builtin_amdgcn_s_barrier();
  __builtin_amdgcn_sched_barrier(0);
  RDB(d0, bqA);

  for (int j = 0; j < NITER; ++j) {
    const bool nl = (j + 1 < NITER);
    const int t2 = 2 * j + 2, t3 = 2 * j + 3;
    SA(2 * j + 1, 1);       PH(d0, 0, bqA, -1);
    if (nl) SB(t2, 0, 0);   PH(d0, 1, bqA, -1);
    if (nl) SB(t2, 0, 1);   PH(d0, 2, bqA, nl ? 4 : 2);
    RDB(d1, bqB);           PH(d0, 3, bqA, nl ? 2 : 0);
    if (nl) SA(t2, 0);      PH(d1, 0, bqB, -1);
    if (nl) SB(t3, 1, 0);   PH(d1, 1, bqB, -1);
    if (nl) SB(t3, 1, 1);   PH(d1, 2, bqB, nl ? 4 : -1);
    if (nl) RDB(d0, bqA);   PH(d1, 3, bqB, nl ? 2 : -1);
  }

  const int row0 = bm * 128 + wm * 64 + lg * 4;
  const int col0 = bn * 128 + wn * 32 + lm;
#pragma unroll
  for (int mi = 0; mi < 4; ++mi) {
#pragma unroll
    for (int ni = 0; ni < 2; ++ni) {
      int col = col0 + ni * 16;
      float bia = BIAS ? bias[col] : 0.f;
#pragma unroll
      for (int rg = 0; rg < 4; ++rg) {
        int row = row0 + mi * 16 + rg;
        float vv = acc[mi][ni][rg] + bia;
        if (RELU) vv = vv > 0.f ? vv : 0.f;
        if (OUT_BF16)
          ((unsigned short*)Cp)[(size_t)row * Ndim + col] = f2bf(vv);
        else
          ((float*)Cp)[(size_t)row * Ndim + col] = vv;
      }
    }
  }
}

// ---- LN kernels: one wave per 768-wide row, 4 rows per block ----
__global__ __launch_bounds__(256) void ln0_k(const unsigned short* __restrict__ x,
                                             const float* __restrict__ g,
                                             const float* __restrict__ bb,
                                             unsigned short* __restrict__ out) {
  int w = threadIdx.x >> 6, lane = threadIdx.x & 63;
  long row = (long)blockIdx.x * 4 + w;
  const unsigned short* xr = x + row * HIDD;
  float xv[12];
  float s1 = 0.f, s2 = 0.f;
#pragma unroll
  for (int c = 0; c < 3; ++c) {
    us4 u = *(const us4*)(xr + c * 256 + lane * 4);
#pragma unroll
    for (int j = 0; j < 4; ++j) {
      float f = bf2f(u[j]);
      xv[c * 4 + j] = f; s1 += f; s2 += f * f;
    }
  }
#pragma unroll
  for (int off = 32; off; off >>= 1) { s1 += __shfl_xor(s1, off); s2 += __shfl_xor(s2, off); }
  float m = s1 * (1.f / 768.f);
  float rs = rsqrtf(s2 * (1.f / 768.f) - m * m + 1e-5f);
#pragma unroll
  for (int c = 0; c < 3; ++c) {
    int cb = c * 256 + lane * 4;
    us4 o;
#pragma unroll
    for (int j = 0; j < 4; ++j) o[j] = f2bf((xv[c * 4 + j] - m) * rs * g[cb + j] + bb[cb + j]);
    *(us4*)(out + row * HIDD + cb) = o;
  }
}

__global__ __launch_bounds__(256) void ln1_k(const unsigned short* __restrict__ ctx,
                                             const unsigned short* __restrict__ hp,
                                             const float* __restrict__ g,
                                             const float* __restrict__ bb,
                                             unsigned short* __restrict__ h2b) {
  int w = threadIdx.x >> 6, lane = threadIdx.x & 63;
  long row = (long)blockIdx.x * 4 + w;
  const unsigned short* xr = ctx + row * HIDD;
  float xv[12];
  float s1 = 0.f, s2 = 0.f;
#pragma unroll
  for (int c = 0; c < 3; ++c) {
    us4 u = *(const us4*)(xr + c * 256 + lane * 4);
#pragma unroll
    for (int j = 0; j < 4; ++j) {
      float f = bf2f(u[j]);
      xv[c * 4 + j] = f; s1 += f; s2 += f * f;
    }
  }
#pragma unroll
  for (int off = 32; off; off >>= 1) { s1 += __shfl_xor(s1, off); s2 += __shfl_xor(s2, off); }
  float m = s1 * (1.f / 768.f);
  float rs = rsqrtf(s2 * (1.f / 768.f) - m * m + 1e-5f);
#pragma unroll
  for (int c = 0; c < 3; ++c) {
    int cb = c * 256 + lane * 4;
    us4 hv = *(const us4*)(hp + row * HIDD + cb);
    us4 ob;
#pragma unroll
    for (int j = 0; j < 4; ++j)
      ob[j] = f2bf(bf2f(hv[j]) + (xv[c * 4 + j] - m) * rs * g[cb + j] + bb[cb + j]);
    *(us4*)(h2b + row * HIDD + cb) = ob;
  }
}

// ln2: out_fp32 = h2(bf16) + LN(mlp2 bf16)
__global__ __launch_bounds__(256) void ln2_k(const unsigned short* __restrict__ m2b,
                                             const unsigned short* __restrict__ h2b,
                                             const float* __restrict__ g,
                                             const float* __restrict__ bb,
                                             float* __restrict__ outp) {
  int w = threadIdx.x >> 6, lane = threadIdx.x & 63;
  long row = (long)blockIdx.x * 4 + w;
  const unsigned short* xr = m2b + row * HIDD;
  float xv[12];
  float s1 = 0.f, s2 = 0.f;
#pragma unroll
  for (int c = 0; c < 3; ++c) {
    us4 u = *(const us4*)(xr + c * 256 + lane * 4);
#pragma unroll
    for (int j = 0; j < 4; ++j) {
      float f = bf2f(u[j]);
      xv[c * 4 + j] = f; s1 += f; s2 += f * f;
    }
  }
#pragma unroll
  for (int off = 32; off; off >>= 1) { s1 += __shfl_xor(s1, off); s2 += __shfl_xor(s2, off); }
  float m = s1 * (1.f / 768.f);
  float rs = rsqrtf(s2 * (1.f / 768.f) - m * m + 1e-5f);
#pragma unroll
  for (int c = 0; c < 3; ++c) {
    int cb = c * 256 + lane * 4;
    us4 hv = *(const us4*)(h2b + row * HIDD + cb);
    fl4 o;
#pragma unroll
    for (int j = 0; j < 4; ++j)
      o[j] = bf2f(hv[j]) + (xv[c * 4 + j] - m) * rs * g[cb + j] + bb[cb + j];
    *(fl4*)(outp + row * HIDD + cb) = o;
  }
}

// ---- fused attention over interleaved qkv[tok][2304] ----
__global__ __launch_bounds__(256, 2) void attn_k(const unsigned short* __restrict__ qkv,
                                                 unsigned short* __restrict__ ctx) {
  __shared__ __align__(16) unsigned short Ks[NPAT * 64];
  __shared__ __align__(16) unsigned short VT[64 * 232];
  __shared__ __align__(16) unsigned short PL[4][16 * 40];
  const int b = blockIdx.x / NHEAD, h = blockIdx.x % NHEAD;
  const int t = threadIdx.x, lane = t & 63, w = t >> 6;
  const size_t base = ((size_t)b * NPAT) * QKVS + h * HDIM;

  for (int idx = t; idx < NPAT * 8; idx += 256) {
    int row = idx >> 3, s = idx & 7;
    us8 kv = *(const us8*)&qkv[base + 768 + (size_t)row * QKVS + s * 8];
    *(us8*)((char*)Ks + row * 128 + ((s ^ (row & 7)) << 4)) = kv;
  }
  for (int idx = t; idx < 98 * 64; idx += 256) {
    int pp = idx >> 6, d = idx & 63;
    unsigned int val = (unsigned int)qkv[base + 1536 + (size_t)(2 * pp) * QKVS + d]
                     | ((unsigned int)qkv[base + 1536 + (size_t)(2 * pp + 1) * QKVS + d] << 16);
    *(unsigned int*)&VT[d * 232 + 2 * pp] = val;
  }
  for (int idx = t; idx < 64 * 18; idx += 256) {
    int d = idx / 18, c = idx % 18;
    *(unsigned int*)&VT[d * 232 + 196 + 2 * c] = 0;
  }
  __syncthreads();

  unsigned short* plw = (unsigned short*)PL[w];
  const int lm = lane & 15, lg = lane >> 4, lk = lg * 8;

  for (int qt = w; qt < 13; qt += 4) {
    const int q0 = qt * 16;
    int qrow = q0 + lm; if (qrow > NPAT - 1) qrow = NPAT - 1;
    short8 af0 = *(const short8*)&qkv[base + (size_t)qrow * QKVS + lk];
    short8 af1 = *(const short8*)&qkv[base + (size_t)qrow * QKVS + 32 + lk];

    f32x4 sc[13];
#pragma unroll
    for (int kt = 0; kt < 13; ++kt) {
      int krow = kt * 16 + lm; if (krow > NPAT - 1) krow = NPAT - 1;
      const char* krp = (const char*)Ks + krow * 128;
      short8 b0 = *(const short8*)(krp + (((lg ^ (krow & 7)) & 7) << 4));
      short8 b1 = *(const short8*)(krp + ((((lg + 4) ^ (krow & 7)) & 7) << 4));
      f32x4 z = (f32x4){0.f, 0.f, 0.f, 0.f};
      z = MFMA16(af0, b0, z);
      sc[kt] = MFMA16(af1, b1, z);
    }
#pragma unroll
    for (int kt = 0; kt < 13; ++kt) {
      int col = kt * 16 + lm;
#pragma unroll
      for (int rg = 0; rg < 4; ++rg) {
        float s = sc[kt][rg] * 0.125f;
        sc[kt][rg] = (col < NPAT) ? s : -1e30f;
      }
    }
    float inv[4];
#pragma unroll
    for (int rg = 0; rg < 4; ++rg) {
      float m = -1e30f;
#pragma unroll
      for (int kt = 0; kt < 13; ++kt) m = fmaxf(m, sc[kt][rg]);
      m = fmaxf(m, __shfl_xor(m, 1)); m = fmaxf(m, __shfl_xor(m, 2));
      m = fmaxf(m, __shfl_xor(m, 4)); m = fmaxf(m, __shfl_xor(m, 8));
      float s = 0.f;
#pragma unroll
      for (int kt = 0; kt < 13; ++kt) { float e = __expf(sc[kt][rg] - m); sc[kt][rg] = e; s += e; }
      s += __shfl_xor(s, 1); s += __shfl_xor(s, 2); s += __shfl_xor(s, 4); s += __shfl_xor(s, 8);
      inv[rg] = 1.f / s;
    }

    f32x4 oacc[4];
#pragma unroll
    for (int ni = 0; ni < 4; ++ni) oacc[ni] = (f32x4){0.f, 0.f, 0.f, 0.f};
#pragma unroll
    for (int kc = 0; kc < 7; ++kc) {
#pragma unroll
      for (int sub = 0; sub < 2; ++sub) {
        const int kt = 2 * kc + sub;
#pragma unroll
        for (int rg = 0; rg < 4; ++rg) {
          unsigned short pv_ = 0;
          if (kt < 13) pv_ = f2bf(sc[kt][rg] * inv[rg]);
          plw[(lg * 4 + rg) * 40 + sub * 16 + lm] = pv_;
        }
      }
      asm volatile("s_waitcnt lgkmcnt(0)" ::: "memory");
      __builtin_amdgcn_sched_barrier(0);
      short8 pa = *(const short8*)&plw[lm * 40 + lk];
#pragma unroll
      for (int ni = 0; ni < 4; ++ni) {
        short8 bv = *(const short8*)&VT[(ni * 16 + lm) * 232 + kc * 32 + lk];
        oacc[ni] = MFMA16(pa, bv, oacc[ni]);
      }
    }
#pragma unroll
    for (int rg = 0; rg < 4; ++rg) {
      int r = q0 + lg * 4 + rg;
      if (r < NPAT) {
#pragma unroll
        for (int ni = 0; ni < 4; ++ni)
          ctx[((size_t)b * NPAT + r) * HIDD + h * HDIM + ni * 16 + lm] = f2bf(oacc[ni][rg]);
      }
    }
  }
}

extern "C" void kernel_launch(void* const* d_in, const int* in_sizes, int n_in,
                              void* d_out, int out_size, void* d_ws, size_t ws_size,
                              hipStream_t stream) {
  const float* x    = (const float*)d_in[0];
  const float* q_w  = (const float*)d_in[1];
  const float* q_b  = (const float*)d_in[2];
  const float* k_w  = (const float*)d_in[3];
  const float* k_b  = (const float*)d_in[4];
  const float* v_w  = (const float*)d_in[5];
  const float* v_b  = (const float*)d_in[6];
  const float* w1   = (const float*)d_in[7];
  const float* b1   = (const float*)d_in[8];
  const float* w2   = (const float*)d_in[9];
  const float* b2   = (const float*)d_in[10];
  const float* ln0g = (const float*)d_in[11];
  const float* ln0b = (const float*)d_in[12];
  const float* ln1g = (const float*)d_in[13];
  const float* ln1b = (const float*)d_in[14];
  const float* ln2g = (const float*)d_in[15];
  const float* ln2b = (const float*)d_in[16];

  char* ws = (char*)d_ws;
  size_t o = 0;
  auto alloc = [&](size_t bytes) { size_t r = o; o += (bytes + 255) & ~(size_t)255; return r; };

  const size_t RSZ = (size_t)NTOK * HIDD * 2;
  unsigned short* Mb    = (unsigned short*)(ws + alloc(256 * 256 * 2));
  unsigned short* wqkvb = (unsigned short*)(ws + alloc((size_t)QKVS * HIDD * 2));
  unsigned short* w1b   = (unsigned short*)(ws + alloc((size_t)FFD * HIDD * 2));
  unsigned short* w2b   = (unsigned short*)(ws + alloc((size_t)HIDD * FFD * 2));
  float*          qkvbias = (float*)(ws + alloc(QKVS * 4));
  char* rA  = ws + alloc(RSZ);   // hp bf16 -> mlp2 bf16
  char* rB  = ws + alloc(RSZ);   // hb (ln0 out) -> h2 bf16
  char* rC0 = ws + alloc(RSZ);   // x bf16 -> ctx -> mlp1[0:RSZ]
  char* rC1 = ws + alloc(RSZ);   // qkv low   -> mlp1[RSZ:2RSZ]
  char* rC2 = ws + alloc(RSZ);   // qkv mid
  char* rC3 = ws + alloc(RSZ);   // qkv high
  (void)rC2; (void)rC3; (void)n_in; (void)in_sizes; (void)ws_size;

  unsigned short* xb  = (unsigned short*)rC0;
  unsigned short* hpb = (unsigned short*)rA;
  unsigned short* hb  = (unsigned short*)rB;
  unsigned short* qkv = (unsigned short*)rC1;  // [25088][2304] spans rC1..rC3
  unsigned short* cxb = (unsigned short*)rC0;  // ctx (x dead after highpass)
  unsigned short* h2b = (unsigned short*)rB;   // hb dead after QKV
  unsigned short* m1b = (unsigned short*)rC0;  // mlp1 full: 154MB spans rC0..rC3
  unsigned short* m2b = (unsigned short*)rA;   // mlp2 bf16 (hp dead after ln1)

  // fused prologue: block0 builds M, block1 concats qkv bias
  prep_k<<<2, 256, 0, stream>>>(q_b, k_b, v_b, qkvbias, Mb);

  auto cgrid = [](long n4) { long g = (n4 + 255) / 256; return (int)(g > 2048 ? 2048 : g); };
  long nx4 = (long)NTOK * HIDD / 4;
  castk<<<cgrid(nx4), 256, 0, stream>>>(x, xb, nx4);
  // fused weight cast: wqkvb||w1b||w2b are contiguous 256-aligned regions
  wcast<<<cgrid(WT_END / 4), 256, 0, stream>>>(q_w, k_w, v_w, w1, w2, wqkvb);

  // highpass: (75264 x 256) @ M^T via gemm128: 1176 blocks, 2/CU
  gemm128<1, 0, 0><<<588 * 2, 512, 0, stream>>>(xb, Mb, nullptr, hpb, 75264, 256, 256);
  ln0_k<<<NTOK / 4, 256, 0, stream>>>(hpb, ln0g, ln0b, hb);

  // fused QKV: gemm256 v3, 98 x 9 = 882 blocks, K=768 (NT=12)
  gemm256<1, 1, 0><<<98 * 9, 512, 0, stream>>>(hb, wqkvb, qkvbias, qkv, NTOK, QKVS, HIDD);

  attn_k<<<128 * NHEAD, 256, 0, stream>>>(qkv, cxb);

  ln1_k<<<NTOK / 4, 256, 0, stream>>>(cxb, hpb, ln1g, ln1b, h2b);

  // mlp1: gemm256 v3, 98 x 12 = 1176 blocks, K=768 (NT=12)
  gemm256<1, 1, 1><<<98 * 12, 512, 0, stream>>>(h2b, w1b, b1, m1b, NTOK, FFD, HIDD);
  // mlp2: gemm128, bf16 out -> rA: 196 x 6 = 1176 blocks, 2/CU, K=3072
  gemm128<1, 1, 0><<<196 * 6, 512, 0, stream>>>(m1b, w2b, b2, m2b, NTOK, HIDD, FFD);

  // final: d_out = h2 + LN(mlp2), fp32 straight out
  ln2_k<<<NTOK / 4, 256, 0, stream>>>(m2b, h2b, ln2g, ln2b, (float*)d_out);
  (void)out_size;
}

// Round 19
// 581.316 us; speedup vs baseline: 1.0257x; 1.0004x over previous
//
#include <hip/hip_runtime.h>

#define NTOK   25088          // B*P = 128*196
#define HIDD   768
#define NHEAD  12
#define HDIM   64
#define FFD    3072
#define NPAT   196
#define QKVS   2304           // interleaved qkv row stride

typedef __attribute__((ext_vector_type(8))) short short8;
typedef __attribute__((ext_vector_type(8))) __bf16 bf16x8;
typedef __attribute__((ext_vector_type(4))) float f32x4;
typedef __attribute__((ext_vector_type(4))) float fl4;
typedef __attribute__((ext_vector_type(4))) unsigned short us4;
typedef __attribute__((ext_vector_type(8))) unsigned short us8;

#define AS1 __attribute__((address_space(1)))
#define AS3 __attribute__((address_space(3)))

__device__ __forceinline__ unsigned short f2bf(float f) {
  unsigned int u = __builtin_bit_cast(unsigned int, f);
  u += 0x7FFFu + ((u >> 16) & 1u);
  return (unsigned short)(u >> 16);
}
__device__ __forceinline__ float bf2f(unsigned short h) {
  unsigned int u = ((unsigned int)h) << 16;
  return __builtin_bit_cast(float, u);
}

// ---- MFMA wrapper: SFINAE over builtin operand type (short8 vs bf16x8) ----
template <typename A>
__device__ __forceinline__ auto mfma_sel(A a, A b, f32x4 c, int)
    -> decltype(__builtin_amdgcn_mfma_f32_16x16x32_bf16(a, b, c, 0, 0, 0)) {
  return __builtin_amdgcn_mfma_f32_16x16x32_bf16(a, b, c, 0, 0, 0);
}
template <typename A>
__device__ __forceinline__ auto mfma_sel(A a, A b, f32x4 c, long)
    -> decltype(__builtin_amdgcn_mfma_f32_16x16x32_bf16(
           __builtin_bit_cast(bf16x8, a), __builtin_bit_cast(bf16x8, b), c, 0, 0, 0)) {
  return __builtin_amdgcn_mfma_f32_16x16x32_bf16(
      __builtin_bit_cast(bf16x8, a), __builtin_bit_cast(bf16x8, b), c, 0, 0, 0);
}
__device__ __forceinline__ f32x4 MFMA16(short8 a, short8 b, f32x4 c) {
  return mfma_sel(a, b, c, 0);
}

__device__ __forceinline__ void gload16(const void* g, void* l) {
  __builtin_amdgcn_global_load_lds((const AS1 void*)g, (AS3 void*)l, 16, 0, 0);
}

// T1: bijective XCD-aware block swizzle (m204).
__device__ __forceinline__ int swz_bid(int nwg) {
  int orig = (int)blockIdx.x;
  int xcd = orig & 7;
  int q = nwg >> 3, r = nwg & 7;
  int base = (xcd < r) ? xcd * (q + 1) : r * (q + 1) + (xcd - r) * q;
  return base + (orig >> 3);
}

// ---- fused prologue: block 0 builds the 256x256 highpass operator (bf16),
// block 1 concats q_b,k_b,v_b -> [2304] fp32 ----
__global__ __launch_bounds__(256) void prep_k(const float* __restrict__ qb,
                                              const float* __restrict__ kb,
                                              const float* __restrict__ vb,
                                              float* __restrict__ biasd,
                                              unsigned short* __restrict__ Mb) {
  if (blockIdx.x == 0) {
    __shared__ float Cs[16], Ss[16];
    int t = threadIdx.x;
    if (t < 16) {
      float c = 0.f;
      for (int k = -4; k <= 3; ++k) c += cosf(0.39269908169872414f * (float)(k * t));
      Cs[t] = c;
      Ss[t] = -sinf(1.5707963267948966f * (float)t);
    }
    __syncthreads();
    int r = t >> 4, cc = t & 15;
    for (int j = 0; j < 256; ++j) {
      int dr = (r - (j >> 4)) & 15;
      int dc = (cc - (j & 15)) & 15;
      float val = ((t == j) ? 1.f : 0.f) - (Cs[dr] * Cs[dc] - Ss[dr] * Ss[dc]) * 0.00390625f;
      Mb[t * 256 + j] = f2bf(val);
    }
  } else {
    for (int i = threadIdx.x; i < QKVS; i += 256)
      biasd[i] = (i < 768) ? qb[i] : (i < 1536) ? kb[i - 768] : vb[i - 1536];
  }
}

// ---- fp32 -> bf16 cast (x only) ----
__global__ __launch_bounds__(256) void castk(const float* __restrict__ s,
                                             unsigned short* __restrict__ d, long n4) {
  for (long i = (long)blockIdx.x * 256 + threadIdx.x; i < n4; i += (long)gridDim.x * 256) {
    fl4 v = *(const fl4*)(s + i * 4);
    us4 o;
    o[0] = f2bf(v[0]); o[1] = f2bf(v[1]); o[2] = f2bf(v[2]); o[3] = f2bf(v[3]);
    *(us4*)(d + i * 4) = o;
  }
}

// ---- fused cast of all weights into contiguous wqkvb||w1b||w2b ----
#define WQ_END  589824          // 768*768
#define WK_END  1179648
#define WV_END  1769472
#define W1_END  4128768         // + 3072*768
#define WT_END  6488064         // + 3072*768
__global__ __launch_bounds__(256) void wcast(const float* __restrict__ qw,
                                             const float* __restrict__ kw,
                                             const float* __restrict__ vw,
                                             const float* __restrict__ w1,
                                             const float* __restrict__ w2,
                                             unsigned short* __restrict__ d) {
  for (long c = (long)blockIdx.x * 256 + threadIdx.x; c < WT_END / 4;
       c += (long)gridDim.x * 256) {
    long i = c * 4;
    const float* s; long off;
    if (i < WQ_END)       { s = qw; off = i; }
    else if (i < WK_END)  { s = kw; off = i - WQ_END; }
    else if (i < WV_END)  { s = vw; off = i - WK_END; }
    else if (i < W1_END)  { s = w1; off = i - WV_END; }
    else                  { s = w2; off = i - W1_END; }
    fl4 v = *(const fl4*)(s + off);
    us4 o;
    o[0] = f2bf(v[0]); o[1] = f2bf(v[1]); o[2] = f2bf(v[2]); o[3] = f2bf(v[3]);
    *(us4*)(d + i) = o;
  }
}

// ---- 256x256x64 GEMM v3: A triple-buffer, B single-buffer, 4 phases/tile,
// one counted vmcnt per tile. LDS A0/A1/A2/B = 128KB. Kdim % 384 == 0.
template <int OUT_BF16, int BIAS, int RELU>
__global__ __launch_bounds__(512, 2) void gemm256(const unsigned short* __restrict__ A,
                                                  const unsigned short* __restrict__ Bm,
                                                  const float* __restrict__ bias,
                                                  void* __restrict__ Cp,
                                                  int Mdim, int Ndim, int Kdim) {
  __shared__ __align__(16) char lds[131072];
  const int nbn = Ndim >> 8;
  const int bid = swz_bid((int)gridDim.x);
  const int bm = bid / nbn, bn = bid % nbn;
  const int t = threadIdx.x;
  const int lane = t & 63, w = t >> 6;
  const int wm = w >> 2, wn = w & 3;
  const int lm = lane & 15, lg = lane >> 4;
  const int NT = Kdim >> 6;          // K-tiles of 64; NT % 6 == 0

  const int tr = t >> 3;
  const int scol = ((t & 7) ^ (tr & 7)) * 8;
  const unsigned short* Asrc = A + (size_t)(bm * 256 + tr) * Kdim + scol;
  const unsigned short* Bsrc = Bm + (size_t)(bn * 256 + tr) * Kdim + scol;
  const size_t K64 = (size_t)64 * Kdim, K128 = (size_t)128 * Kdim, K192 = (size_t)192 * Kdim;

  char* const A0 = lds;
  char* const A1 = lds + 32768;
  char* const A2 = lds + 65536;
  char* const Bb = lds + 98304;

  auto SA = [&](int kt, char* abuf) {
    const unsigned short* s = Asrc + kt * 64;
    gload16(s, abuf + t * 16);
    gload16(s + K64, abuf + 8192 + t * 16);
    gload16(s + K128, abuf + 16384 + t * 16);
    gload16(s + K192, abuf + 24576 + t * 16);
  };
  auto SB = [&](int kt) {
    const unsigned short* s = Bsrc + kt * 64;
    gload16(s, Bb + t * 16);
    gload16(s + K64, Bb + 8192 + t * 16);
    gload16(s + K128, Bb + 16384 + t * 16);
    gload16(s + K192, Bb + 24576 + t * 16);
  };

  const int sx = lm & 7;
  int slotb[2];
#pragma unroll
  for (int kk = 0; kk < 2; ++kk) slotb[kk] = (((kk << 2) | lg) ^ sx) << 4;
  const int aoff = wm * 16384 + lm * 128;
  const int boff = (wn >> 1) * 16384 + ((wn & 1) * 64 + lm) * 128;

  f32x4 acc[8][4];
#pragma unroll
  for (int i = 0; i < 8; ++i)
#pragma unroll
    for (int j = 0; j < 4; ++j) acc[i][j] = (f32x4){0.f, 0.f, 0.f, 0.f};
  short8 bqA[4][2], bqB[4][2];

  auto RDB = [&](short8 (&bq)[4][2]) {
#pragma unroll
    for (int ni = 0; ni < 4; ++ni)
#pragma unroll
      for (int kk = 0; kk < 2; ++kk)
        bq[ni][kk] = *(const short8*)(Bb + boff + ni * 2048 + slotb[kk]);
  };
  auto PH = [&](const char* abuf, int q, short8 (&bq)[4][2], int vmc) {
    short8 aq[2][2];
#pragma unroll
    for (int m2 = 0; m2 < 2; ++m2)
#pragma unroll
      for (int kk = 0; kk < 2; ++kk)
        aq[m2][kk] = *(const short8*)(abuf + aoff + q * 4096 + m2 * 2048 + slotb[kk]);
    __builtin_amdgcn_s_barrier();
    asm volatile("s_waitcnt lgkmcnt(0)" ::: "memory");
    __builtin_amdgcn_sched_barrier(0);
    __builtin_amdgcn_s_setprio(1);
#pragma unroll
    for (int kk = 0; kk < 2; ++kk)
#pragma unroll
      for (int m2 = 0; m2 < 2; ++m2)
#pragma unroll
        for (int ni = 0; ni < 4; ++ni)
          acc[q * 2 + m2][ni] = MFMA16(aq[m2][kk], bq[ni][kk], acc[q * 2 + m2][ni]);
    __builtin_amdgcn_s_setprio(0);
    if (vmc == 4)      asm volatile("s_waitcnt vmcnt(4)" ::: "memory");
    else if (vmc == 0) asm volatile("s_waitcnt vmcnt(0)" ::: "memory");
    __builtin_amdgcn_s_barrier();
    __builtin_amdgcn_sched_barrier(0);
  };

  auto TILE = [&](int i, char* curA, char* nxtA, short8 (&cur)[4][2], short8 (&nxt)[4][2]) {
    const bool h1 = (i + 1 < NT), h2 = (i + 2 < NT);
    if (h1) SB(i + 1);
    if (h2) SA(i + 2, nxtA);
    PH(curA, 0, cur, -1);                              // P1
    PH(curA, 1, cur, -1);                              // P2
    PH(curA, 2, cur, h2 ? 4 : (h1 ? 0 : -1));          // P3 (the one wait)
    if (h1) RDB(nxt);
    PH(curA, 3, cur, -1);                              // P4
  };

  SA(0, A0); SB(0); SA(1, A1);
  asm volatile("s_waitcnt vmcnt(4)" ::: "memory");
  __builtin_amdgcn_s_barrier();
  __builtin_amdgcn_sched_barrier(0);
  RDB(bqA);
  asm volatile("s_waitcnt lgkmcnt(0)" ::: "memory");
  __builtin_amdgcn_sched_barrier(0);
  __builtin_amdgcn_s_barrier();
  __builtin_amdgcn_sched_barrier(0);

  for (int J = 0; J < NT / 6; ++J) {
    const int b6 = J * 6;
    TILE(b6 + 0, A0, A2, bqA, bqB);
    TILE(b6 + 1, A1, A0, bqB, bqA);
    TILE(b6 + 2, A2, A1, bqA, bqB);
    TILE(b6 + 3, A0, A2, bqB, bqA);
    TILE(b6 + 4, A1, A0, bqA, bqB);
    TILE(b6 + 5, A2, A1, bqB, bqA);
  }

  const int row0 = bm * 256 + wm * 128 + lg * 4;
  const int col0 = bn * 256 + wn * 64 + lm;
#pragma unroll
  for (int mi = 0; mi < 8; ++mi) {
#pragma unroll
    for (int ni = 0; ni < 4; ++ni) {
      int col = col0 + ni * 16;
      float bia = BIAS ? bias[col] : 0.f;
#pragma unroll
      for (int rg = 0; rg < 4; ++rg) {
        int row = row0 + mi * 16 + rg;
        float vv = acc[mi][ni][rg] + bia;
        if (RELU) vv = vv > 0.f ? vv : 0.f;
        if (OUT_BF16)
          ((unsigned short*)Cp)[(size_t)row * Ndim + col] = f2bf(vv);
        else
          ((float*)Cp)[(size_t)row * Ndim + col] = vv;
      }
    }
  }
}

// ---- 128x128x64 GEMM, 8-phase schedule, 64KB LDS -> 2 blocks/CU ----
template <int OUT_BF16, int BIAS, int RELU>
__global__ __launch_bounds__(512, 4) void gemm128(const unsigned short* __restrict__ A,
                                                  const unsigned short* __restrict__ Bm,
                                                  const float* __restrict__ bias,
                                                  void* __restrict__ Cp,
                                                  int Mdim, int Ndim, int Kdim) {
  __shared__ __align__(16) char lds[65536];
  const int nbn = Ndim >> 7;
  const int bid = swz_bid((int)gridDim.x);
  const int bm = bid / nbn, bn = bid % nbn;
  const int t = threadIdx.x;
  const int lane = t & 63, w = t >> 6;
  const int wm = w >> 2, wn = w & 3;
  const int lm = lane & 15, lg = lane >> 4;
  const int NITER = Kdim >> 7;   // K-tiles of 64, 2 per iter

  const int tr = t >> 3;
  const int scol = ((t & 7) ^ (tr & 7)) * 8;
  const unsigned short* Asrc = A + (size_t)(bm * 128 + tr) * Kdim + scol;
  const unsigned short* Bsrc = Bm + (size_t)(bn * 128 + tr) * Kdim + scol;
  const size_t K64 = (size_t)64 * Kdim;

  char* const d0 = lds;
  char* const d1 = lds + 32768;

  auto SA = [&](int kt, int d) {
    char* dst = lds + d * 32768;
    const unsigned short* s = Asrc + kt * 64;
    gload16(s, dst + t * 16);
    gload16(s + K64, dst + 8192 + t * 16);
  };
  auto SB = [&](int kt, int d, int h) {
    char* dst = lds + d * 32768 + 16384 + h * 8192;
    gload16(Bsrc + kt * 64 + (h ? K64 : 0), dst + t * 16);
  };

  const int sx = lm & 7;
  int slotb[2];
#pragma unroll
  for (int kk = 0; kk < 2; ++kk) slotb[kk] = (((kk << 2) | lg) ^ sx) << 4;
  const int aoff = (wm * 64 + lm) * 128;
  const int boff = 16384 + (wn * 32 + lm) * 128;

  f32x4 acc[4][2];
#pragma unroll
  for (int i = 0; i < 4; ++i)
#pragma unroll
    for (int j = 0; j < 2; ++j) acc[i][j] = (f32x4){0.f, 0.f, 0.f, 0.f};
  short8 bqA[2][2], bqB[2][2];

  auto RDB = [&](const char* db, short8 (&bq)[2][2]) {
#pragma unroll
    for (int ni = 0; ni < 2; ++ni)
#pragma unroll
      for (int kk = 0; kk < 2; ++kk)
        bq[ni][kk] = *(const short8*)(db + boff + ni * 2048 + slotb[kk]);
  };
  auto PH = [&](const char* db, int q, short8 (&bq)[2][2], int vmc) {
    short8 aq[2];
#pragma unroll
    for (int kk = 0; kk < 2; ++kk)
      aq[kk] = *(const short8*)(db + aoff + q * 2048 + slotb[kk]);
    __builtin_amdgcn_s_barrier();
    asm volatile("s_waitcnt lgkmcnt(0)" ::: "memory");
    __builtin_amdgcn_sched_barrier(0);
    __builtin_amdgcn_s_setprio(1);
#pragma unroll
    for (int kk = 0; kk < 2; ++kk)
#pragma unroll
      for (int ni = 0; ni < 2; ++ni)
        acc[q][ni] = MFMA16(aq[kk], bq[ni][kk], acc[q][ni]);
    __builtin_amdgcn_s_setprio(0);
    if (vmc == 4)      asm volatile("s_waitcnt vmcnt(4)" ::: "memory");
    else if (vmc == 2) asm volatile("s_waitcnt vmcnt(2)" ::: "memory");
    else if (vmc == 0) asm volatile("s_waitcnt vmcnt(0)" ::: "memory");
    __builtin_amdgcn_s_barrier();
    __builtin_amdgcn_sched_barrier(0);
  };

  SA(0, 0); SB(0, 0, 0); SB(0, 0, 1); SB(1, 1, 0); SB(1, 1, 1);
  asm volatile("s_waitcnt vmcnt(2)" ::: "memory");
  __builtin_amdgcn_s_barrier();
  __builtin_amdgcn_sched_barrier(0);
  RDB(d0, bqA);

  for (int j = 0; j < NITER; ++j) {
    const bool nl = (j + 1 < NITER);
    const int t2 = 2 * j + 2, t3 = 2 * j + 3;
    SA(2 * j + 1, 1);       PH(d0, 0, bqA, -1);
    if (nl) SB(t2, 0, 0);   PH(d0, 1, bqA, -1);
    if (nl) SB(t2, 0, 1);   PH(d0, 2, bqA, nl ? 4 : 2);
    RDB(d1, bqB);           PH(d0, 3, bqA, nl ? 2 : 0);
    if (nl) SA(t2, 0);      PH(d1, 0, bqB, -1);
    if (nl) SB(t3, 1, 0);   PH(d1, 1, bqB, -1);
    if (nl) SB(t3, 1, 1);   PH(d1, 2, bqB, nl ? 4 : -1);
    if (nl) RDB(d0, bqA);   PH(d1, 3, bqB, nl ? 2 : -1);
  }

  const int row0 = bm * 128 + wm * 64 + lg * 4;
  const int col0 = bn * 128 + wn * 32 + lm;
#pragma unroll
  for (int mi = 0; mi < 4; ++mi) {
#pragma unroll
    for (int ni = 0; ni < 2; ++ni) {
      int col = col0 + ni * 16;
      float bia = BIAS ? bias[col] : 0.f;
#pragma unroll
      for (int rg = 0; rg < 4; ++rg) {
        int row = row0 + mi * 16 + rg;
        float vv = acc[mi][ni][rg] + bia;
        if (RELU) vv = vv > 0.f ? vv : 0.f;
        if (OUT_BF16)
          ((unsigned short*)Cp)[(size_t)row * Ndim + col] = f2bf(vv);
        else
          ((float*)Cp)[(size_t)row * Ndim + col] = vv;
      }
    }
  }
}

// ---- LN kernels: one wave per 768-wide row, 4 rows per block ----
__global__ __launch_bounds__(256) void ln0_k(const unsigned short* __restrict__ x,
                                             const float* __restrict__ g,
                                             const float* __restrict__ bb,
                                             unsigned short* __restrict__ out) {
  int w = threadIdx.x >> 6, lane = threadIdx.x & 63;
  long row = (long)blockIdx.x * 4 + w;
  const unsigned short* xr = x + row * HIDD;
  float xv[12];
  float s1 = 0.f, s2 = 0.f;
#pragma unroll
  for (int c = 0; c < 3; ++c) {
    us4 u = *(const us4*)(xr + c * 256 + lane * 4);
#pragma unroll
    for (int j = 0; j < 4; ++j) {
      float f = bf2f(u[j]);
      xv[c * 4 + j] = f; s1 += f; s2 += f * f;
    }
  }
#pragma unroll
  for (int off = 32; off; off >>= 1) { s1 += __shfl_xor(s1, off); s2 += __shfl_xor(s2, off); }
  float m = s1 * (1.f / 768.f);
  float rs = rsqrtf(s2 * (1.f / 768.f) - m * m + 1e-5f);
#pragma unroll
  for (int c = 0; c < 3; ++c) {
    int cb = c * 256 + lane * 4;
    us4 o;
#pragma unroll
    for (int j = 0; j < 4; ++j) o[j] = f2bf((xv[c * 4 + j] - m) * rs * g[cb + j] + bb[cb + j]);
    *(us4*)(out + row * HIDD + cb) = o;
  }
}

__global__ __launch_bounds__(256) void ln1_k(const unsigned short* __restrict__ ctx,
                                             const unsigned short* __restrict__ hp,
                                             const float* __restrict__ g,
                                             const float* __restrict__ bb,
                                             unsigned short* __restrict__ h2b) {
  int w = threadIdx.x >> 6, lane = threadIdx.x & 63;
  long row = (long)blockIdx.x * 4 + w;
  const unsigned short* xr = ctx + row * HIDD;
  float xv[12];
  float s1 = 0.f, s2 = 0.f;
#pragma unroll
  for (int c = 0; c < 3; ++c) {
    us4 u = *(const us4*)(xr + c * 256 + lane * 4);
#pragma unroll
    for (int j = 0; j < 4; ++j) {
      float f = bf2f(u[j]);
      xv[c * 4 + j] = f; s1 += f; s2 += f * f;
    }
  }
#pragma unroll
  for (int off = 32; off; off >>= 1) { s1 += __shfl_xor(s1, off); s2 += __shfl_xor(s2, off); }
  float m = s1 * (1.f / 768.f);
  float rs = rsqrtf(s2 * (1.f / 768.f) - m * m + 1e-5f);
#pragma unroll
  for (int c = 0; c < 3; ++c) {
    int cb = c * 256 + lane * 4;
    us4 hv = *(const us4*)(hp + row * HIDD + cb);
    us4 ob;
#pragma unroll
    for (int j = 0; j < 4; ++j)
      ob[j] = f2bf(bf2f(hv[j]) + (xv[c * 4 + j] - m) * rs * g[cb + j] + bb[cb + j]);
    *(us4*)(h2b + row * HIDD + cb) = ob;
  }
}

// ln2: out_fp32 = h2(bf16) + LN(mlp2 bf16)
__global__ __launch_bounds__(256) void ln2_k(const unsigned short* __restrict__ m2b,
                                             const unsigned short* __restrict__ h2b,
                                             const float* __restrict__ g,
                                             const float* __restrict__ bb,
                                             float* __restrict__ outp) {
  int w = threadIdx.x >> 6, lane = threadIdx.x & 63;
  long row = (long)blockIdx.x * 4 + w;
  const unsigned short* xr = m2b + row * HIDD;
  float xv[12];
  float s1 = 0.f, s2 = 0.f;
#pragma unroll
  for (int c = 0; c < 3; ++c) {
    us4 u = *(const us4*)(xr + c * 256 + lane * 4);
#pragma unroll
    for (int j = 0; j < 4; ++j) {
      float f = bf2f(u[j]);
      xv[c * 4 + j] = f; s1 += f; s2 += f * f;
    }
  }
#pragma unroll
  for (int off = 32; off; off >>= 1) { s1 += __shfl_xor(s1, off); s2 += __shfl_xor(s2, off); }
  float m = s1 * (1.f / 768.f);
  float rs = rsqrtf(s2 * (1.f / 768.f) - m * m + 1e-5f);
#pragma unroll
  for (int c = 0; c < 3; ++c) {
    int cb = c * 256 + lane * 4;
    us4 hv = *(const us4*)(h2b + row * HIDD + cb);
    fl4 o;
#pragma unroll
    for (int j = 0; j < 4; ++j)
      o[j] = bf2f(hv[j]) + (xv[c * 4 + j] - m) * rs * g[cb + j] + bb[cb + j];
    *(fl4*)(outp + row * HIDD + cb) = o;
  }
}

// ---- fused attention over interleaved qkv[tok][2304] ----
__global__ __launch_bounds__(256, 2) void attn_k(const unsigned short* __restrict__ qkv,
                                                 unsigned short* __restrict__ ctx) {
  __shared__ __align__(16) unsigned short Ks[NPAT * 64];
  __shared__ __align__(16) unsigned short VT[64 * 232];
  __shared__ __align__(16) unsigned short PL[4][16 * 40];
  const int b = blockIdx.x / NHEAD, h = blockIdx.x % NHEAD;
  const int t = threadIdx.x, lane = t & 63, w = t >> 6;
  const size_t base = ((size_t)b * NPAT) * QKVS + h * HDIM;

  for (int idx = t; idx < NPAT * 8; idx += 256) {
    int row = idx >> 3, s = idx & 7;
    us8 kv = *(const us8*)&qkv[base + 768 + (size_t)row * QKVS + s * 8];
    *(us8*)((char*)Ks + row * 128 + ((s ^ (row & 7)) << 4)) = kv;
  }
  for (int idx = t; idx < 98 * 64; idx += 256) {
    int pp = idx >> 6, d = idx & 63;
    unsigned int val = (unsigned int)qkv[base + 1536 + (size_t)(2 * pp) * QKVS + d]
                     | ((unsigned int)qkv[base + 1536 + (size_t)(2 * pp + 1) * QKVS + d] << 16);
    *(unsigned int*)&VT[d * 232 + 2 * pp] = val;
  }
  for (int idx = t; idx < 64 * 18; idx += 256) {
    int d = idx / 18, c = idx % 18;
    *(unsigned int*)&VT[d * 232 + 196 + 2 * c] = 0;
  }
  __syncthreads();

  unsigned short* plw = (unsigned short*)PL[w];
  const int lm = lane & 15, lg = lane >> 4, lk = lg * 8;

  for (int qt = w; qt < 13; qt += 4) {
    const int q0 = qt * 16;
    int qrow = q0 + lm; if (qrow > NPAT - 1) qrow = NPAT - 1;
    short8 af0 = *(const short8*)&qkv[base + (size_t)qrow * QKVS + lk];
    short8 af1 = *(const short8*)&qkv[base + (size_t)qrow * QKVS + 32 + lk];

    f32x4 sc[13];
#pragma unroll
    for (int kt = 0; kt < 13; ++kt) {
      int krow = kt * 16 + lm; if (krow > NPAT - 1) krow = NPAT - 1;
      const char* krp = (const char*)Ks + krow * 128;
      short8 b0 = *(const short8*)(krp + (((lg ^ (krow & 7)) & 7) << 4));
      short8 b1 = *(const short8*)(krp + ((((lg + 4) ^ (krow & 7)) & 7) << 4));
      f32x4 z = (f32x4){0.f, 0.f, 0.f, 0.f};
      z = MFMA16(af0, b0, z);
      sc[kt] = MFMA16(af1, b1, z);
    }
#pragma unroll
    for (int kt = 0; kt < 13; ++kt) {
      int col = kt * 16 + lm;
#pragma unroll
      for (int rg = 0; rg < 4; ++rg) {
        float s = sc[kt][rg] * 0.125f;
        sc[kt][rg] = (col < NPAT) ? s : -1e30f;
      }
    }
    float inv[4];
#pragma unroll
    for (int rg = 0; rg < 4; ++rg) {
      float m = -1e30f;
#pragma unroll
      for (int kt = 0; kt < 13; ++kt) m = fmaxf(m, sc[kt][rg]);
      m = fmaxf(m, __shfl_xor(m, 1)); m = fmaxf(m, __shfl_xor(m, 2));
      m = fmaxf(m, __shfl_xor(m, 4)); m = fmaxf(m, __shfl_xor(m, 8));
      float s = 0.f;
#pragma unroll
      for (int kt = 0; kt < 13; ++kt) { float e = __expf(sc[kt][rg] - m); sc[kt][rg] = e; s += e; }
      s += __shfl_xor(s, 1); s += __shfl_xor(s, 2); s += __shfl_xor(s, 4); s += __shfl_xor(s, 8);
      inv[rg] = 1.f / s;
    }

    f32x4 oacc[4];
#pragma unroll
    for (int ni = 0; ni < 4; ++ni) oacc[ni] = (f32x4){0.f, 0.f, 0.f, 0.f};
#pragma unroll
    for (int kc = 0; kc < 7; ++kc) {
#pragma unroll
      for (int sub = 0; sub < 2; ++sub) {
        const int kt = 2 * kc + sub;
#pragma unroll
        for (int rg = 0; rg < 4; ++rg) {
          unsigned short pv_ = 0;
          if (kt < 13) pv_ = f2bf(sc[kt][rg] * inv[rg]);
          plw[(lg * 4 + rg) * 40 + sub * 16 + lm] = pv_;
        }
      }
      asm volatile("s_waitcnt lgkmcnt(0)" ::: "memory");
      __builtin_amdgcn_sched_barrier(0);
      short8 pa = *(const short8*)&plw[lm * 40 + lk];
#pragma unroll
      for (int ni = 0; ni < 4; ++ni) {
        short8 bv = *(const short8*)&VT[(ni * 16 + lm) * 232 + kc * 32 + lk];
        oacc[ni] = MFMA16(pa, bv, oacc[ni]);
      }
    }
#pragma unroll
    for (int rg = 0; rg < 4; ++rg) {
      int r = q0 + lg * 4 + rg;
      if (r < NPAT) {
#pragma unroll
        for (int ni = 0; ni < 4; ++ni)
          ctx[((size_t)b * NPAT + r) * HIDD + h * HDIM + ni * 16 + lm] = f2bf(oacc[ni][rg]);
      }
    }
  }
}

extern "C" void kernel_launch(void* const* d_in, const int* in_sizes, int n_in,
                              void* d_out, int out_size, void* d_ws, size_t ws_size,
                              hipStream_t stream) {
  const float* x    = (const float*)d_in[0];
  const float* q_w  = (const float*)d_in[1];
  const float* q_b  = (const float*)d_in[2];
  const float* k_w  = (const float*)d_in[3];
  const float* k_b  = (const float*)d_in[4];
  const float* v_w  = (const float*)d_in[5];
  const float* v_b  = (const float*)d_in[6];
  const float* w1   = (const float*)d_in[7];
  const float* b1   = (const float*)d_in[8];
  const float* w2   = (const float*)d_in[9];
  const float* b2   = (const float*)d_in[10];
  const float* ln0g = (const float*)d_in[11];
  const float* ln0b = (const float*)d_in[12];
  const float* ln1g = (const float*)d_in[13];
  const float* ln1b = (const float*)d_in[14];
  const float* ln2g = (const float*)d_in[15];
  const float* ln2b = (const float*)d_in[16];

  char* ws = (char*)d_ws;
  size_t o = 0;
  auto alloc = [&](size_t bytes) { size_t r = o; o += (bytes + 255) & ~(size_t)255; return r; };

  const size_t RSZ = (size_t)NTOK * HIDD * 2;
  unsigned short* Mb    = (unsigned short*)(ws + alloc(256 * 256 * 2));
  unsigned short* wqkvb = (unsigned short*)(ws + alloc((size_t)QKVS * HIDD * 2));
  unsigned short* w1b   = (unsigned short*)(ws + alloc((size_t)FFD * HIDD * 2));
  unsigned short* w2b   = (unsigned short*)(ws + alloc((size_t)HIDD * FFD * 2));
  float*          qkvbias = (float*)(ws + alloc(QKVS * 4));
  char* rA  = ws + alloc(RSZ);   // hp bf16 -> mlp2 bf16
  char* rB  = ws + alloc(RSZ);   // hb (ln0 out) -> h2 bf16
  char* rC0 = ws + alloc(RSZ);   // x bf16 -> ctx -> mlp1[0:RSZ]
  char* rC1 = ws + alloc(RSZ);   // qkv low   -> mlp1[RSZ:2RSZ]
  char* rC2 = ws + alloc(RSZ);   // qkv mid
  char* rC3 = ws + alloc(RSZ);   // qkv high
  (void)rC2; (void)rC3; (void)n_in; (void)in_sizes; (void)ws_size;

  unsigned short* xb  = (unsigned short*)rC0;
  unsigned short* hpb = (unsigned short*)rA;
  unsigned short* hb  = (unsigned short*)rB;
  unsigned short* qkv = (unsigned short*)rC1;  // [25088][2304] spans rC1..rC3
  unsigned short* cxb = (unsigned short*)rC0;  // ctx (x dead after highpass)
  unsigned short* h2b = (unsigned short*)rB;   // hb dead after QKV
  unsigned short* m1b = (unsigned short*)rC0;  // mlp1 full: 154MB spans rC0..rC3
  unsigned short* m2b = (unsigned short*)rA;   // mlp2 bf16 (hp dead after ln1)

  // fused prologue: block0 builds M, block1 concats qkv bias
  prep_k<<<2, 256, 0, stream>>>(q_b, k_b, v_b, qkvbias, Mb);

  auto cgrid = [](long n4) { long g = (n4 + 255) / 256; return (int)(g > 2048 ? 2048 : g); };
  long nx4 = (long)NTOK * HIDD / 4;
  castk<<<cgrid(nx4), 256, 0, stream>>>(x, xb, nx4);
  // fused weight cast: wqkvb||w1b||w2b are contiguous 256-aligned regions
  wcast<<<cgrid(WT_END / 4), 256, 0, stream>>>(q_w, k_w, v_w, w1, w2, wqkvb);

  // highpass: (75264 x 256) @ M^T via gemm128: 1176 blocks, 2/CU
  gemm128<1, 0, 0><<<588 * 2, 512, 0, stream>>>(xb, Mb, nullptr, hpb, 75264, 256, 256);
  ln0_k<<<NTOK / 4, 256, 0, stream>>>(hpb, ln0g, ln0b, hb);

  // fused QKV: gemm256 v3, 98 x 9 = 882 blocks, K=768 (NT=12)
  gemm256<1, 1, 0><<<98 * 9, 512, 0, stream>>>(hb, wqkvb, qkvbias, qkv, NTOK, QKVS, HIDD);

  attn_k<<<128 * NHEAD, 256, 0, stream>>>(qkv, cxb);

  ln1_k<<<NTOK / 4, 256, 0, stream>>>(cxb, hpb, ln1g, ln1b, h2b);

  // mlp1: gemm256 v3, 98 x 12 = 1176 blocks, K=768 (NT=12)
  gemm256<1, 1, 1><<<98 * 12, 512, 0, stream>>>(h2b, w1b, b1, m1b, NTOK, FFD, HIDD);
  // mlp2: gemm128, bf16 out -> rA: 196 x 6 = 1176 blocks, 2/CU, K=3072
  gemm128<1, 1, 0><<<196 * 6, 512, 0, stream>>>(m1b, w2b, b2, m2b, NTOK, HIDD, FFD);

  // final: d_out = h2 + LN(mlp2), fp32 straight out
  ln2_k<<<NTOK / 4, 256, 0, stream>>>(m2b, h2b, ln2g, ln2b, (float*)d_out);
  (void)out_size;
}